// Round 3
// baseline (205.322 us; speedup 1.0000x reference)
//
#include <hip/hip_runtime.h>

#define Bb 2
#define Tt 2048
#define Cc_ 1024
#define Hh 16
#define HDd 64

typedef __attribute__((ext_vector_type(8))) short bf16x8;
typedef __attribute__((ext_vector_type(4))) float f32x4;
typedef __attribute__((ext_vector_type(4))) unsigned short u16x4;

__device__ __forceinline__ unsigned short f2bf(float f) {
  union { float f; unsigned int u; } v; v.f = f;
  unsigned int r = v.u + 0x7FFFu + ((v.u >> 16) & 1u);
  return (unsigned short)(r >> 16);
}
__device__ __forceinline__ float bf2f(unsigned short u) {
  union { unsigned int u; float f; } v; v.u = ((unsigned int)u) << 16;
  return v.f;
}
__device__ __forceinline__ f32x4 mfma16(bf16x8 a, bf16x8 b, f32x4 c) {
  return __builtin_amdgcn_mfma_f32_16x16x32_bf16(a, b, c, 0, 0, 0);
}
__device__ __forceinline__ void gl_lds16(const void* g, void* l) {
  auto* gp = reinterpret_cast<const __attribute__((address_space(1))) unsigned int*>(
      reinterpret_cast<unsigned long long>(g));
  auto* lp = reinterpret_cast<__attribute__((address_space(3))) unsigned int*>(
      reinterpret_cast<unsigned long long>(l));
  __builtin_amdgcn_global_load_lds(gp, lp, 16, 0, 0);
}

// ---------------- fp32 -> bf16 elementwise (x) ----------------
__global__ __launch_bounds__(256) void k_cvt(const float* __restrict__ in,
                                             unsigned short* __restrict__ out, int n4) {
  const int i = blockIdx.x * 256 + threadIdx.x;
  if (i >= n4) return;
  f32x4 v = ((const f32x4*)in)[i];
  u16x4 o;
  o[0] = f2bf(v[0]); o[1] = f2bf(v[1]); o[2] = f2bf(v[2]); o[3] = f2bf(v[3]);
  ((u16x4*)out)[i] = o;
}

// ---------------- fp32 [R][Cc] -> bf16 [Cc][R] transpose ----------------
__global__ __launch_bounds__(256) void k_tcvt(const float* __restrict__ in,
                                              unsigned short* __restrict__ out, int R, int Cc) {
  __shared__ float tile[32][33];
  const int c0 = blockIdx.x * 32, r0 = blockIdx.y * 32;
  const int tx = threadIdx.x, ty = threadIdx.y;  // (32,8)
#pragma unroll
  for (int i = 0; i < 4; ++i)
    tile[ty + i * 8][tx] = in[(size_t)(r0 + ty + i * 8) * Cc + c0 + tx];
  __syncthreads();
#pragma unroll
  for (int i = 0; i < 4; ++i)
    out[(size_t)(c0 + ty + i * 8) * R + r0 + tx] = f2bf(tile[tx][ty + i * 8]);
}

// ---------------- bf16 GEMM 128x128: C[M][N] = A[M][K] * Bt[N][K]^T ----------------
template <bool OUT_BF16>
__global__ __launch_bounds__(256) void k_gemm(const unsigned short* __restrict__ A,
                                              const unsigned short* __restrict__ Bt,
                                              void* __restrict__ Cout, int M, int N, int K) {
  __shared__ unsigned short lA[128 * 64];
  __shared__ unsigned short lB[128 * 64];
  const int tid = threadIdx.x;
  const int lane = tid & 63, wid = tid >> 6;
  const int wr = wid >> 1, wc = wid & 1;
  const int bm = blockIdx.y * 128, bn = blockIdx.x * 128;
  const int l15 = lane & 15, l4 = lane >> 4;
  f32x4 acc[4][4];
#pragma unroll
  for (int i = 0; i < 4; ++i)
#pragma unroll
    for (int j = 0; j < 4; ++j) acc[i][j] = f32x4{0.f, 0.f, 0.f, 0.f};
  const int nk = K >> 6;
  for (int t = 0; t < nk; ++t) {
    const int k0 = t << 6;
    __syncthreads();
#pragma unroll
    for (int i = 0; i < 4; ++i) {
      const int slot = i * 256 + tid;
      const int row = slot >> 3, g = slot & 7;
      const int gs = (g ^ (row & 7)) * 8;
      gl_lds16(A + (size_t)(bm + row) * K + k0 + gs, &lA[slot * 8]);
      gl_lds16(Bt + (size_t)(bn + row) * K + k0 + gs, &lB[slot * 8]);
    }
    __syncthreads();
#pragma unroll
    for (int ks = 0; ks < 2; ++ks) {
      bf16x8 af[4], bfr[4];
#pragma unroll
      for (int mf = 0; mf < 4; ++mf) {
        const int row = wr * 64 + mf * 16 + l15;
        const int g = ks * 4 + l4;
        af[mf] = *(const bf16x8*)&lA[row * 64 + ((g ^ (row & 7)) * 8)];
      }
#pragma unroll
      for (int nf = 0; nf < 4; ++nf) {
        const int row = wc * 64 + nf * 16 + l15;
        const int g = ks * 4 + l4;
        bfr[nf] = *(const bf16x8*)&lB[row * 64 + ((g ^ (row & 7)) * 8)];
      }
#pragma unroll
      for (int mf = 0; mf < 4; ++mf)
#pragma unroll
        for (int nf = 0; nf < 4; ++nf)
          acc[mf][nf] = mfma16(af[mf], bfr[nf], acc[mf][nf]);
    }
  }
  const int rb = bm + wr * 64 + l4 * 4;
  const int cb = bn + wc * 64 + l15;
#pragma unroll
  for (int mf = 0; mf < 4; ++mf)
#pragma unroll
    for (int nf = 0; nf < 4; ++nf)
#pragma unroll
      for (int j = 0; j < 4; ++j) {
        const size_t idx = (size_t)(rb + mf * 16 + j) * N + cb + nf * 16;
        if (OUT_BF16)
          ((unsigned short*)Cout)[idx] = f2bf(acc[mf][nf][j]);
        else
          ((float*)Cout)[idx] = acc[mf][nf][j];
      }
}

// ---------------- bf16 GEMM 128x64 tile (for small N): more blocks/CU ----------------
__global__ __launch_bounds__(256) void k_gemm64(const unsigned short* __restrict__ A,
                                                const unsigned short* __restrict__ Bt,
                                                float* __restrict__ Cout, int M, int N, int K) {
  __shared__ unsigned short lA[128 * 64];
  __shared__ unsigned short lB[64 * 64];
  const int tid = threadIdx.x;
  const int lane = tid & 63, w = tid >> 6;  // wave owns rows w*32..w*32+31
  const int bm = blockIdx.y * 128, bn = blockIdx.x * 64;
  const int l15 = lane & 15, l4 = lane >> 4;
  f32x4 acc[2][4];
#pragma unroll
  for (int i = 0; i < 2; ++i)
#pragma unroll
    for (int j = 0; j < 4; ++j) acc[i][j] = f32x4{0.f, 0.f, 0.f, 0.f};
  const int nk = K >> 6;
  for (int t = 0; t < nk; ++t) {
    const int k0 = t << 6;
    __syncthreads();
#pragma unroll
    for (int i = 0; i < 4; ++i) {
      const int slot = i * 256 + tid;
      const int row = slot >> 3, g = slot & 7;
      const int gs = (g ^ (row & 7)) * 8;
      gl_lds16(A + (size_t)(bm + row) * K + k0 + gs, &lA[slot * 8]);
    }
#pragma unroll
    for (int i = 0; i < 2; ++i) {
      const int slot = i * 256 + tid;
      const int row = slot >> 3, g = slot & 7;
      const int gs = (g ^ (row & 7)) * 8;
      gl_lds16(Bt + (size_t)(bn + row) * K + k0 + gs, &lB[slot * 8]);
    }
    __syncthreads();
#pragma unroll
    for (int ks = 0; ks < 2; ++ks) {
      bf16x8 af[2], bfr[4];
#pragma unroll
      for (int mf = 0; mf < 2; ++mf) {
        const int row = w * 32 + mf * 16 + l15;
        const int g = ks * 4 + l4;
        af[mf] = *(const bf16x8*)&lA[row * 64 + ((g ^ (row & 7)) * 8)];
      }
#pragma unroll
      for (int nf = 0; nf < 4; ++nf) {
        const int row = nf * 16 + l15;
        const int g = ks * 4 + l4;
        bfr[nf] = *(const bf16x8*)&lB[row * 64 + ((g ^ (row & 7)) * 8)];
      }
#pragma unroll
      for (int mf = 0; mf < 2; ++mf)
#pragma unroll
        for (int nf = 0; nf < 4; ++nf)
          acc[mf][nf] = mfma16(af[mf], bfr[nf], acc[mf][nf]);
    }
  }
  const int rb = bm + w * 32 + l4 * 4;
  const int cb = bn + l15;
#pragma unroll
  for (int mf = 0; mf < 2; ++mf)
#pragma unroll
    for (int nf = 0; nf < 4; ++nf)
#pragma unroll
      for (int j = 0; j < 4; ++j)
        Cout[(size_t)(rb + mf * 16 + j) * N + cb + nf * 16] = acc[mf][nf][j];
}

// ---------------- RoPE + repack Q,K to [B,H,T,64] bf16 ----------------
// Q pre-scaled by hd^-0.5 * log2(e) so attention works in exp2 domain.
__global__ __launch_bounds__(256) void k_rope(const unsigned short* __restrict__ qkv,
                                              const float* __restrict__ rsin,
                                              const float* __restrict__ rcos,
                                              unsigned short* __restrict__ Q,
                                              unsigned short* __restrict__ K) {
  const int tid = blockIdx.x * 256 + threadIdx.x;  // 2^21 total
  const int d = tid & 31;
  const int t = (tid >> 5) & 2047;
  const int h = (tid >> 16) & 15;
  const int b = tid >> 20;
  const size_t rq = (size_t)(b * Tt + t) * 3072 + h * 192;
  const float q1 = bf2f(qkv[rq + d]), q2 = bf2f(qkv[rq + 32 + d]);
  const float k1 = bf2f(qkv[rq + 64 + d]), k2 = bf2f(qkv[rq + 96 + d]);
  const float s = rsin[t * 32 + d], c = rcos[t * 32 + d];
  const size_t ob = ((size_t)(b * Hh + h) * Tt + t) * 64 + d;
  const float qs = 0.125f * 1.44269504088896f;  // hd^-0.5 * log2(e)
  Q[ob] = f2bf((q1 * c - q2 * s) * qs);
  Q[ob + 32] = f2bf((q1 * s + q2 * c) * qs);
  K[ob] = f2bf(k1 * c - k2 * s);
  K[ob + 32] = f2bf(k1 * s + k2 * c);
}

// ---------------- V repack: qkv v-cols -> Vt [B*H][64][T] bf16 ----------------
__global__ __launch_bounds__(256) void k_vrep(const unsigned short* __restrict__ qkv,
                                              unsigned short* __restrict__ Vt) {
  __shared__ unsigned short tile[32][72];
  const int bh = blockIdx.y;
  const int t0 = blockIdx.x * 32;
  const int tx = threadIdx.x, ty = threadIdx.y;  // (32,8)
  const int b = bh >> 4, h = bh & 15;
#pragma unroll
  for (int i = 0; i < 4; ++i) {
    const int trow = ty + i * 8;
    const size_t r = (size_t)(b * Tt + t0 + trow) * 3072 + h * 192 + 128;
    tile[trow][tx] = qkv[r + tx];
    tile[trow][tx + 32] = qkv[r + 32 + tx];
  }
  __syncthreads();
#pragma unroll
  for (int i = 0; i < 8; ++i) {
    const int d = ty + i * 8;
    Vt[((size_t)bh * 64 + d) * Tt + t0 + tx] = tile[tx][d];
  }
}

// ---------------- causal flash attention ----------------
// grid (32 qtile-pairs, 32 bh), 128 thr (2 waves). QBLK=32 (16 rows/wave), KVBLK=64.
// Pairing (63-bx, bx): 33 uniform tile-steps/block. Double-buffered K/V with
// prefetch (T3-min): STAGE(next) -> compute(cur) -> vmcnt(0)+barrier.
// exp2-domain softmax (log2e folded into Q scale). T13 defer-max. T5 setprio.
__global__ __launch_bounds__(128) void k_attn(const unsigned short* __restrict__ Q,
                                              const unsigned short* __restrict__ Kt,
                                              const unsigned short* __restrict__ Vt,
                                              unsigned short* __restrict__ Aout) {
  __shared__ unsigned short lK[2][64 * 64];
  __shared__ unsigned short lV[2][64 * 64];
  __shared__ unsigned short lP[2][16 * 64];
  const int bxq = blockIdx.x, bh = blockIdx.y;
  const int b = bh >> 4, h = bh & 15;
  const int tid = threadIdx.x, lane = tid & 63, w = tid >> 6;  // w in {0,1}
  const int l15 = lane & 15, l4 = lane >> 4;
  const unsigned short* Kbh = Kt + (size_t)bh * Tt * 64;
  const unsigned short* Vbh = Vt + (size_t)bh * 64 * Tt;
  unsigned short* lPw = lP[w];

#define STAGE(buf, tt)                                                     \
  {                                                                        \
    const int kv0s = (tt) * 64;                                            \
    _Pragma("unroll") for (int i = 0; i < 4; ++i) {                        \
      const int slot = i * 128 + tid;                                      \
      const int row = slot >> 3, g = slot & 7;                             \
      const int gs = (g ^ (row & 7)) * 8;                                  \
      gl_lds16(Kbh + (size_t)(kv0s + row) * 64 + gs, &lK[buf][slot * 8]);  \
      gl_lds16(Vbh + (size_t)row * Tt + kv0s + gs, &lV[buf][slot * 8]);    \
    }                                                                      \
  }

  for (int ph = 0; ph < 2; ++ph) {
    const int qt = ph ? bxq : (63 - bxq);
    const int qb = qt * 32;
    const size_t qoff = ((size_t)bh * Tt + qb + w * 16 + l15) * 64 + l4 * 8;
    const bf16x8 qf0 = *(const bf16x8*)&Q[qoff];
    const bf16x8 qf1 = *(const bf16x8*)&Q[qoff + 32];
    f32x4 o[4];
#pragma unroll
    for (int i = 0; i < 4; ++i) o[i] = f32x4{0.f, 0.f, 0.f, 0.f};
    float mrun = -1e30f, lrun = 0.f;  // stats for q-row (w*16 + l15), log2 domain
    const int nt = (qt >> 1) + 1;
    // prologue: stage tile 0
    STAGE(0, 0);
    asm volatile("s_waitcnt vmcnt(0)" ::: "memory");
    __builtin_amdgcn_s_barrier();
    for (int t = 0; t < nt; ++t) {
      const int cur = t & 1;
      const bool more = (t + 1 < nt);
      if (more) STAGE(cur ^ 1, t + 1);  // issue next-tile loads early
      const int kv0 = t * 64;
      // QK^T (swapped): s[nf][j] = score[key=kv0+nf*16+l4*4+j][qrow=qb+w*16+l15]
      f32x4 s[4];
#pragma unroll
      for (int i = 0; i < 4; ++i) s[i] = f32x4{0.f, 0.f, 0.f, 0.f};
      __builtin_amdgcn_s_setprio(1);
#pragma unroll
      for (int ks = 0; ks < 2; ++ks) {
        const bf16x8 qa = ks ? qf1 : qf0;
#pragma unroll
        for (int nf = 0; nf < 4; ++nf) {
          const int row = nf * 16 + l15;
          const int g = ks * 4 + l4;
          const bf16x8 kf = *(const bf16x8*)&lK[cur][row * 64 + ((g ^ (row & 7)) * 8)];
          s[nf] = mfma16(kf, qa, s[nf]);
        }
      }
      __builtin_amdgcn_s_setprio(0);
      if (t == nt - 1) {  // only possibly-partial tile: causal mask (key > qrow)
#pragma unroll
        for (int nf = 0; nf < 4; ++nf)
#pragma unroll
          for (int j = 0; j < 4; ++j)
            if (kv0 + nf * 16 + l4 * 4 + j > qb + w * 16 + l15) s[nf][j] = -3e38f;
      }
      // row max: in-lane tree + 2 cross-l4 shfl
      float mx = fmaxf(fmaxf(fmaxf(s[0][0], s[0][1]), fmaxf(s[0][2], s[0][3])),
                       fmaxf(fmaxf(s[1][0], s[1][1]), fmaxf(s[1][2], s[1][3])));
      mx = fmaxf(mx, fmaxf(fmaxf(fmaxf(s[2][0], s[2][1]), fmaxf(s[2][2], s[2][3])),
                           fmaxf(fmaxf(s[3][0], s[3][1]), fmaxf(s[3][2], s[3][3]))));
      mx = fmaxf(mx, __shfl_xor(mx, 16, 64));
      mx = fmaxf(mx, __shfl_xor(mx, 32, 64));
      const bool need = !__all(mx - mrun <= 8.0f);  // T13 defer-max (log2 units)
      float mnew = mrun;
      if (need) mnew = fmaxf(mrun, mx);
      float ssum = 0.f;
#pragma unroll
      for (int nf = 0; nf < 4; ++nf) {
        u16x4 pk;
#pragma unroll
        for (int j = 0; j < 4; ++j) {
          const float p = exp2f(s[nf][j] - mnew);
          ssum += p;
          pk[j] = f2bf(p);
        }
        const int g0 = nf * 2 + (l4 >> 1);
        *(u16x4*)&lPw[l15 * 64 + ((g0 ^ (l15 & 7)) * 8) + (l4 & 1) * 4] = pk;
      }
      ssum += __shfl_xor(ssum, 16, 64);
      ssum += __shfl_xor(ssum, 32, 64);
      if (need) {
        const float alpha = exp2f(mrun - mnew);
        lrun = lrun * alpha + ssum;
        mrun = mnew;
        float aj[4];
#pragma unroll
        for (int j = 0; j < 4; ++j) aj[j] = __shfl(alpha, l4 * 4 + j, 64);
#pragma unroll
        for (int df = 0; df < 4; ++df)
#pragma unroll
          for (int j = 0; j < 4; ++j) o[df][j] *= aj[j];
      } else {
        lrun += ssum;
      }
      __builtin_amdgcn_s_setprio(1);
#pragma unroll
      for (int kb = 0; kb < 2; ++kb) {
        const bf16x8 pa = *(const bf16x8*)&lPw[l15 * 64 + (((kb * 4 + l4) ^ (l15 & 7)) * 8)];
#pragma unroll
        for (int df = 0; df < 4; ++df) {
          const int row = df * 16 + l15;
          const int g = kb * 4 + l4;
          const bf16x8 vb = *(const bf16x8*)&lV[cur][row * 64 + ((g ^ (row & 7)) * 8)];
          o[df] = mfma16(pa, vb, o[df]);
        }
      }
      __builtin_amdgcn_s_setprio(0);
      if (more) asm volatile("s_waitcnt vmcnt(0)" ::: "memory");  // next tile landed
      __builtin_amdgcn_s_barrier();  // compute(cur) done block-wide; safe to overwrite
    }
    const float rinv = 1.f / lrun;
    float lj[4];
#pragma unroll
    for (int j = 0; j < 4; ++j) lj[j] = __shfl(rinv, l4 * 4 + j, 64);
#pragma unroll
    for (int j = 0; j < 4; ++j) {
      const size_t rr = (size_t)(b * Tt + qb + w * 16 + l4 * 4 + j) * 1024 + h * 64 + l15;
#pragma unroll
      for (int df = 0; df < 4; ++df) Aout[rr + df * 16] = f2bf(o[df][j] * lj[j]);
    }
  }
#undef STAGE
}

extern "C" void kernel_launch(void* const* d_in, const int* in_sizes, int n_in,
                              void* d_out, int out_size, void* d_ws, size_t ws_size,
                              hipStream_t stream) {
  const float* x = (const float*)d_in[0];
  const float* Wqkv = (const float*)d_in[1];
  const float* Wproj = (const float*)d_in[2];
  const float* rsin = (const float*)d_in[3];
  const float* rcos = (const float*)d_in[4];
  float* out = (float*)d_out;
  char* ws = (char*)d_ws;
  // ws layout (MB): xb 0-8, wqkvt 8-14, wprot 14-16, qkv 16-40, Q 40-48, K 48-56, Vt 56-64, attn 64-72
  unsigned short* xb = (unsigned short*)(ws);
  unsigned short* wqkvt = (unsigned short*)(ws + (size_t)(8 << 20));
  unsigned short* wprot = (unsigned short*)(ws + (size_t)(14 << 20));
  unsigned short* qkv = (unsigned short*)(ws + (size_t)(16 << 20));
  unsigned short* Q = (unsigned short*)(ws + (size_t)(40 << 20));
  unsigned short* K = (unsigned short*)(ws + (size_t)(48 << 20));
  unsigned short* Vt = (unsigned short*)(ws + (size_t)(56 << 20));
  unsigned short* attn = (unsigned short*)(ws + (size_t)(64 << 20));

  k_cvt<<<4096, 256, 0, stream>>>(x, xb, 1048576);
  k_tcvt<<<dim3(96, 32), dim3(32, 8), 0, stream>>>(Wqkv, wqkvt, 1024, 3072);
  k_tcvt<<<dim3(32, 32), dim3(32, 8), 0, stream>>>(Wproj, wprot, 1024, 1024);
  k_gemm<true><<<dim3(24, 32), 256, 0, stream>>>(xb, wqkvt, qkv, 4096, 3072, 1024);
  k_rope<<<8192, 256, 0, stream>>>(qkv, rsin, rcos, Q, K);
  k_vrep<<<dim3(64, 32), dim3(32, 8), 0, stream>>>(qkv, Vt);
  k_attn<<<dim3(32, 32), 128, 0, stream>>>(Q, K, Vt, attn);
  k_gemm64<<<dim3(16, 32), 256, 0, stream>>>(attn, wprot, out, 4096, 1024, 1024);
}

// Round 4
// 197.530 us; speedup vs baseline: 1.0394x; 1.0394x over previous
//
#include <hip/hip_runtime.h>

#define Bb 2
#define Tt 2048
#define Cc_ 1024
#define Hh 16
#define HDd 64

typedef __attribute__((ext_vector_type(8))) short bf16x8;
typedef __attribute__((ext_vector_type(4))) float f32x4;
typedef __attribute__((ext_vector_type(4))) unsigned short u16x4;

__device__ __forceinline__ unsigned short f2bf(float f) {
  union { float f; unsigned int u; } v; v.f = f;
  unsigned int r = v.u + 0x7FFFu + ((v.u >> 16) & 1u);
  return (unsigned short)(r >> 16);
}
__device__ __forceinline__ float bf2f(unsigned short u) {
  union { unsigned int u; float f; } v; v.u = ((unsigned int)u) << 16;
  return v.f;
}
__device__ __forceinline__ f32x4 mfma16(bf16x8 a, bf16x8 b, f32x4 c) {
  return __builtin_amdgcn_mfma_f32_16x16x32_bf16(a, b, c, 0, 0, 0);
}
__device__ __forceinline__ void gl_lds16(const void* g, void* l) {
  auto* gp = reinterpret_cast<const __attribute__((address_space(1))) unsigned int*>(
      reinterpret_cast<unsigned long long>(g));
  auto* lp = reinterpret_cast<__attribute__((address_space(3))) unsigned int*>(
      reinterpret_cast<unsigned long long>(l));
  __builtin_amdgcn_global_load_lds(gp, lp, 16, 0, 0);
}

// ---------------- fp32 -> bf16 elementwise (x) ----------------
__global__ __launch_bounds__(256) void k_cvt(const float* __restrict__ in,
                                             unsigned short* __restrict__ out, int n4) {
  const int i = blockIdx.x * 256 + threadIdx.x;
  if (i >= n4) return;
  f32x4 v = ((const f32x4*)in)[i];
  u16x4 o;
  o[0] = f2bf(v[0]); o[1] = f2bf(v[1]); o[2] = f2bf(v[2]); o[3] = f2bf(v[3]);
  ((u16x4*)out)[i] = o;
}

// ---------------- fp32 [R][Cc] -> bf16 [Cc][R] transpose ----------------
__global__ __launch_bounds__(256) void k_tcvt(const float* __restrict__ in,
                                              unsigned short* __restrict__ out, int R, int Cc) {
  __shared__ float tile[32][33];
  const int c0 = blockIdx.x * 32, r0 = blockIdx.y * 32;
  const int tx = threadIdx.x, ty = threadIdx.y;  // (32,8)
#pragma unroll
  for (int i = 0; i < 4; ++i)
    tile[ty + i * 8][tx] = in[(size_t)(r0 + ty + i * 8) * Cc + c0 + tx];
  __syncthreads();
#pragma unroll
  for (int i = 0; i < 4; ++i)
    out[(size_t)(c0 + ty + i * 8) * R + r0 + tx] = f2bf(tile[tx][ty + i * 8]);
}

// ---------------- bf16 GEMM 128x128: C[M][N] = A[M][K] * Bt[N][K]^T ----------------
template <bool OUT_BF16>
__global__ __launch_bounds__(256) void k_gemm(const unsigned short* __restrict__ A,
                                              const unsigned short* __restrict__ Bt,
                                              void* __restrict__ Cout, int M, int N, int K) {
  __shared__ unsigned short lA[128 * 64];
  __shared__ unsigned short lB[128 * 64];
  const int tid = threadIdx.x;
  const int lane = tid & 63, wid = tid >> 6;
  const int wr = wid >> 1, wc = wid & 1;
  const int bm = blockIdx.y * 128, bn = blockIdx.x * 128;
  const int l15 = lane & 15, l4 = lane >> 4;
  f32x4 acc[4][4];
#pragma unroll
  for (int i = 0; i < 4; ++i)
#pragma unroll
    for (int j = 0; j < 4; ++j) acc[i][j] = f32x4{0.f, 0.f, 0.f, 0.f};
  const int nk = K >> 6;
  for (int t = 0; t < nk; ++t) {
    const int k0 = t << 6;
    __syncthreads();
#pragma unroll
    for (int i = 0; i < 4; ++i) {
      const int slot = i * 256 + tid;
      const int row = slot >> 3, g = slot & 7;
      const int gs = (g ^ (row & 7)) * 8;
      gl_lds16(A + (size_t)(bm + row) * K + k0 + gs, &lA[slot * 8]);
      gl_lds16(Bt + (size_t)(bn + row) * K + k0 + gs, &lB[slot * 8]);
    }
    __syncthreads();
#pragma unroll
    for (int ks = 0; ks < 2; ++ks) {
      bf16x8 af[4], bfr[4];
#pragma unroll
      for (int mf = 0; mf < 4; ++mf) {
        const int row = wr * 64 + mf * 16 + l15;
        const int g = ks * 4 + l4;
        af[mf] = *(const bf16x8*)&lA[row * 64 + ((g ^ (row & 7)) * 8)];
      }
#pragma unroll
      for (int nf = 0; nf < 4; ++nf) {
        const int row = wc * 64 + nf * 16 + l15;
        const int g = ks * 4 + l4;
        bfr[nf] = *(const bf16x8*)&lB[row * 64 + ((g ^ (row & 7)) * 8)];
      }
#pragma unroll
      for (int mf = 0; mf < 4; ++mf)
#pragma unroll
        for (int nf = 0; nf < 4; ++nf)
          acc[mf][nf] = mfma16(af[mf], bfr[nf], acc[mf][nf]);
    }
  }
  const int rb = bm + wr * 64 + l4 * 4;
  const int cb = bn + wc * 64 + l15;
#pragma unroll
  for (int mf = 0; mf < 4; ++mf)
#pragma unroll
    for (int nf = 0; nf < 4; ++nf)
#pragma unroll
      for (int j = 0; j < 4; ++j) {
        const size_t idx = (size_t)(rb + mf * 16 + j) * N + cb + nf * 16;
        if (OUT_BF16)
          ((unsigned short*)Cout)[idx] = f2bf(acc[mf][nf][j]);
        else
          ((float*)Cout)[idx] = acc[mf][nf][j];
      }
}

// ---------------- bf16 GEMM 128x64 tile (for small N): more blocks/CU ----------------
__global__ __launch_bounds__(256) void k_gemm64(const unsigned short* __restrict__ A,
                                                const unsigned short* __restrict__ Bt,
                                                float* __restrict__ Cout, int M, int N, int K) {
  __shared__ unsigned short lA[128 * 64];
  __shared__ unsigned short lB[64 * 64];
  const int tid = threadIdx.x;
  const int lane = tid & 63, w = tid >> 6;  // wave owns rows w*32..w*32+31
  const int bm = blockIdx.y * 128, bn = blockIdx.x * 64;
  const int l15 = lane & 15, l4 = lane >> 4;
  f32x4 acc[2][4];
#pragma unroll
  for (int i = 0; i < 2; ++i)
#pragma unroll
    for (int j = 0; j < 4; ++j) acc[i][j] = f32x4{0.f, 0.f, 0.f, 0.f};
  const int nk = K >> 6;
  for (int t = 0; t < nk; ++t) {
    const int k0 = t << 6;
    __syncthreads();
#pragma unroll
    for (int i = 0; i < 4; ++i) {
      const int slot = i * 256 + tid;
      const int row = slot >> 3, g = slot & 7;
      const int gs = (g ^ (row & 7)) * 8;
      gl_lds16(A + (size_t)(bm + row) * K + k0 + gs, &lA[slot * 8]);
    }
#pragma unroll
    for (int i = 0; i < 2; ++i) {
      const int slot = i * 256 + tid;
      const int row = slot >> 3, g = slot & 7;
      const int gs = (g ^ (row & 7)) * 8;
      gl_lds16(Bt + (size_t)(bn + row) * K + k0 + gs, &lB[slot * 8]);
    }
    __syncthreads();
#pragma unroll
    for (int ks = 0; ks < 2; ++ks) {
      bf16x8 af[2], bfr[4];
#pragma unroll
      for (int mf = 0; mf < 2; ++mf) {
        const int row = w * 32 + mf * 16 + l15;
        const int g = ks * 4 + l4;
        af[mf] = *(const bf16x8*)&lA[row * 64 + ((g ^ (row & 7)) * 8)];
      }
#pragma unroll
      for (int nf = 0; nf < 4; ++nf) {
        const int row = nf * 16 + l15;
        const int g = ks * 4 + l4;
        bfr[nf] = *(const bf16x8*)&lB[row * 64 + ((g ^ (row & 7)) * 8)];
      }
#pragma unroll
      for (int mf = 0; mf < 2; ++mf)
#pragma unroll
        for (int nf = 0; nf < 4; ++nf)
          acc[mf][nf] = mfma16(af[mf], bfr[nf], acc[mf][nf]);
    }
  }
  const int rb = bm + w * 32 + l4 * 4;
  const int cb = bn + l15;
#pragma unroll
  for (int mf = 0; mf < 2; ++mf)
#pragma unroll
    for (int nf = 0; nf < 4; ++nf)
#pragma unroll
      for (int j = 0; j < 4; ++j)
        Cout[(size_t)(rb + mf * 16 + j) * N + cb + nf * 16] = acc[mf][nf][j];
}

// ---------------- RoPE + repack Q,K to [B,H,T,64] bf16 ----------------
// Q pre-scaled by hd^-0.5 * log2(e) so attention works in exp2 domain.
__global__ __launch_bounds__(256) void k_rope(const unsigned short* __restrict__ qkv,
                                              const float* __restrict__ rsin,
                                              const float* __restrict__ rcos,
                                              unsigned short* __restrict__ Q,
                                              unsigned short* __restrict__ K) {
  const int tid = blockIdx.x * 256 + threadIdx.x;  // 2^21 total
  const int d = tid & 31;
  const int t = (tid >> 5) & 2047;
  const int h = (tid >> 16) & 15;
  const int b = tid >> 20;
  const size_t rq = (size_t)(b * Tt + t) * 3072 + h * 192;
  const float q1 = bf2f(qkv[rq + d]), q2 = bf2f(qkv[rq + 32 + d]);
  const float k1 = bf2f(qkv[rq + 64 + d]), k2 = bf2f(qkv[rq + 96 + d]);
  const float s = rsin[t * 32 + d], c = rcos[t * 32 + d];
  const size_t ob = ((size_t)(b * Hh + h) * Tt + t) * 64 + d;
  const float qs = 0.125f * 1.44269504088896f;  // hd^-0.5 * log2(e)
  Q[ob] = f2bf((q1 * c - q2 * s) * qs);
  Q[ob + 32] = f2bf((q1 * s + q2 * c) * qs);
  K[ob] = f2bf(k1 * c - k2 * s);
  K[ob + 32] = f2bf(k1 * s + k2 * c);
}

// ---------------- V repack: qkv v-cols -> Vt [B*H][64][T] bf16 ----------------
__global__ __launch_bounds__(256) void k_vrep(const unsigned short* __restrict__ qkv,
                                              unsigned short* __restrict__ Vt) {
  __shared__ unsigned short tile[32][72];
  const int bh = blockIdx.y;
  const int t0 = blockIdx.x * 32;
  const int tx = threadIdx.x, ty = threadIdx.y;  // (32,8)
  const int b = bh >> 4, h = bh & 15;
#pragma unroll
  for (int i = 0; i < 4; ++i) {
    const int trow = ty + i * 8;
    const size_t r = (size_t)(b * Tt + t0 + trow) * 3072 + h * 192 + 128;
    tile[trow][tx] = qkv[r + tx];
    tile[trow][tx + 32] = qkv[r + 32 + tx];
  }
  __syncthreads();
#pragma unroll
  for (int i = 0; i < 8; ++i) {
    const int d = ty + i * 8;
    Vt[((size_t)bh * 64 + d) * Tt + t0 + tx] = tile[tx][d];
  }
}

// ---------------- causal flash attention ----------------
// 512 blocks x 256 thr (4 waves). QBLK=64 (16 rows/wave), KVBLK=64.
// XCD-aware decode: bh = (bid&7)*4 + (bid>>3)/16 -> each bh's 16 blocks live on
// ONE XCD; per-XCD K/V working set 2 MB < 4 MB L2. Pairing (31-bxq, bxq): 33
// uniform steps. Double-buffered K/V prefetch (T3-min): STAGE(next) -> compute
// -> vmcnt(0)+barrier. exp2-domain softmax, T13 defer-max, T5 setprio.
__global__ __launch_bounds__(256) void k_attn(const unsigned short* __restrict__ Q,
                                              const unsigned short* __restrict__ Kt,
                                              const unsigned short* __restrict__ Vt,
                                              unsigned short* __restrict__ Aout) {
  __shared__ unsigned short lK[2][64 * 64];
  __shared__ unsigned short lV[2][64 * 64];
  __shared__ unsigned short lP[4][16 * 64];
  const int bid = blockIdx.x;
  const int slot0 = bid >> 3;
  const int bh = (bid & 7) * 4 + (slot0 >> 4);
  const int bxq = slot0 & 15;
  const int b = bh >> 4, h = bh & 15;
  const int tid = threadIdx.x, lane = tid & 63, w = tid >> 6;
  const int l15 = lane & 15, l4 = lane >> 4;
  const unsigned short* Kbh = Kt + (size_t)bh * Tt * 64;
  const unsigned short* Vbh = Vt + (size_t)bh * 64 * Tt;
  unsigned short* lPw = lP[w];

#define STAGE(buf, tt)                                                     \
  {                                                                        \
    const int kv0s = (tt) * 64;                                            \
    _Pragma("unroll") for (int i = 0; i < 2; ++i) {                        \
      const int slot = i * 256 + tid;                                      \
      const int row = slot >> 3, g = slot & 7;                             \
      const int gs = (g ^ (row & 7)) * 8;                                  \
      gl_lds16(Kbh + (size_t)(kv0s + row) * 64 + gs, &lK[buf][slot * 8]);  \
      gl_lds16(Vbh + (size_t)row * Tt + kv0s + gs, &lV[buf][slot * 8]);    \
    }                                                                      \
  }

  for (int ph = 0; ph < 2; ++ph) {
    const int qt = ph ? bxq : (31 - bxq);
    const int qb = qt * 64;
    const size_t qoff = ((size_t)bh * Tt + qb + w * 16 + l15) * 64 + l4 * 8;
    const bf16x8 qf0 = *(const bf16x8*)&Q[qoff];
    const bf16x8 qf1 = *(const bf16x8*)&Q[qoff + 32];
    f32x4 o[4];
#pragma unroll
    for (int i = 0; i < 4; ++i) o[i] = f32x4{0.f, 0.f, 0.f, 0.f};
    float mrun = -1e30f, lrun = 0.f;  // stats for q-row (w*16 + l15), log2 domain
    const int nt = qt + 1;
    // prologue: stage tile 0
    STAGE(0, 0);
    asm volatile("s_waitcnt vmcnt(0)" ::: "memory");
    __builtin_amdgcn_s_barrier();
    for (int t = 0; t < nt; ++t) {
      const int cur = t & 1;
      const bool more = (t + 1 < nt);
      if (more) STAGE(cur ^ 1, t + 1);  // issue next-tile loads early
      const int kv0 = t * 64;
      // QK^T (swapped): s[nf][j] = score[key=kv0+nf*16+l4*4+j][qrow=qb+w*16+l15]
      f32x4 s[4];
#pragma unroll
      for (int i = 0; i < 4; ++i) s[i] = f32x4{0.f, 0.f, 0.f, 0.f};
      __builtin_amdgcn_s_setprio(1);
#pragma unroll
      for (int ks = 0; ks < 2; ++ks) {
        const bf16x8 qa = ks ? qf1 : qf0;
#pragma unroll
        for (int nf = 0; nf < 4; ++nf) {
          const int row = nf * 16 + l15;
          const int g = ks * 4 + l4;
          const bf16x8 kf = *(const bf16x8*)&lK[cur][row * 64 + ((g ^ (row & 7)) * 8)];
          s[nf] = mfma16(kf, qa, s[nf]);
        }
      }
      __builtin_amdgcn_s_setprio(0);
      if (t == nt - 1) {  // diagonal tile: causal mask (key > qrow)
#pragma unroll
        for (int nf = 0; nf < 4; ++nf)
#pragma unroll
          for (int j = 0; j < 4; ++j)
            if (nf * 16 + l4 * 4 + j > w * 16 + l15) s[nf][j] = -3e38f;
      }
      // row max: in-lane tree + 2 cross-l4 shfl
      float mx = fmaxf(fmaxf(fmaxf(s[0][0], s[0][1]), fmaxf(s[0][2], s[0][3])),
                       fmaxf(fmaxf(s[1][0], s[1][1]), fmaxf(s[1][2], s[1][3])));
      mx = fmaxf(mx, fmaxf(fmaxf(fmaxf(s[2][0], s[2][1]), fmaxf(s[2][2], s[2][3])),
                           fmaxf(fmaxf(s[3][0], s[3][1]), fmaxf(s[3][2], s[3][3]))));
      mx = fmaxf(mx, __shfl_xor(mx, 16, 64));
      mx = fmaxf(mx, __shfl_xor(mx, 32, 64));
      const bool need = !__all(mx - mrun <= 8.0f);  // T13 defer-max (log2 units)
      float mnew = mrun;
      if (need) mnew = fmaxf(mrun, mx);
      float ssum = 0.f;
#pragma unroll
      for (int nf = 0; nf < 4; ++nf) {
        u16x4 pk;
#pragma unroll
        for (int j = 0; j < 4; ++j) {
          const float p = exp2f(s[nf][j] - mnew);
          ssum += p;
          pk[j] = f2bf(p);
        }
        const int g0 = nf * 2 + (l4 >> 1);
        *(u16x4*)&lPw[l15 * 64 + ((g0 ^ (l15 & 7)) * 8) + (l4 & 1) * 4] = pk;
      }
      ssum += __shfl_xor(ssum, 16, 64);
      ssum += __shfl_xor(ssum, 32, 64);
      if (need) {
        const float alpha = exp2f(mrun - mnew);
        lrun = lrun * alpha + ssum;
        mrun = mnew;
        float aj[4];
#pragma unroll
        for (int j = 0; j < 4; ++j) aj[j] = __shfl(alpha, l4 * 4 + j, 64);
#pragma unroll
        for (int df = 0; df < 4; ++df)
#pragma unroll
          for (int j = 0; j < 4; ++j) o[df][j] *= aj[j];
      } else {
        lrun += ssum;
      }
      __builtin_amdgcn_s_setprio(1);
#pragma unroll
      for (int kb = 0; kb < 2; ++kb) {
        const bf16x8 pa = *(const bf16x8*)&lPw[l15 * 64 + (((kb * 4 + l4) ^ (l15 & 7)) * 8)];
#pragma unroll
        for (int df = 0; df < 4; ++df) {
          const int row = df * 16 + l15;
          const int g = kb * 4 + l4;
          const bf16x8 vb = *(const bf16x8*)&lV[cur][row * 64 + ((g ^ (row & 7)) * 8)];
          o[df] = mfma16(pa, vb, o[df]);
        }
      }
      __builtin_amdgcn_s_setprio(0);
      if (more) asm volatile("s_waitcnt vmcnt(0)" ::: "memory");  // next tile landed
      __builtin_amdgcn_s_barrier();  // compute(cur) done block-wide; safe to overwrite
    }
    const float rinv = 1.f / lrun;
    float lj[4];
#pragma unroll
    for (int j = 0; j < 4; ++j) lj[j] = __shfl(rinv, l4 * 4 + j, 64);
#pragma unroll
    for (int j = 0; j < 4; ++j) {
      const size_t rr = (size_t)(b * Tt + qb + w * 16 + l4 * 4 + j) * 1024 + h * 64 + l15;
#pragma unroll
      for (int df = 0; df < 4; ++df) Aout[rr + df * 16] = f2bf(o[df][j] * lj[j]);
    }
  }
#undef STAGE
}

extern "C" void kernel_launch(void* const* d_in, const int* in_sizes, int n_in,
                              void* d_out, int out_size, void* d_ws, size_t ws_size,
                              hipStream_t stream) {
  const float* x = (const float*)d_in[0];
  const float* Wqkv = (const float*)d_in[1];
  const float* Wproj = (const float*)d_in[2];
  const float* rsin = (const float*)d_in[3];
  const float* rcos = (const float*)d_in[4];
  float* out = (float*)d_out;
  char* ws = (char*)d_ws;
  // ws layout (MB): xb 0-8, wqkvt 8-14, wprot 14-16, qkv 16-40, Q 40-48, K 48-56, Vt 56-64, attn 64-72
  unsigned short* xb = (unsigned short*)(ws);
  unsigned short* wqkvt = (unsigned short*)(ws + (size_t)(8 << 20));
  unsigned short* wprot = (unsigned short*)(ws + (size_t)(14 << 20));
  unsigned short* qkv = (unsigned short*)(ws + (size_t)(16 << 20));
  unsigned short* Q = (unsigned short*)(ws + (size_t)(40 << 20));
  unsigned short* K = (unsigned short*)(ws + (size_t)(48 << 20));
  unsigned short* Vt = (unsigned short*)(ws + (size_t)(56 << 20));
  unsigned short* attn = (unsigned short*)(ws + (size_t)(64 << 20));

  k_cvt<<<4096, 256, 0, stream>>>(x, xb, 1048576);
  k_tcvt<<<dim3(96, 32), dim3(32, 8), 0, stream>>>(Wqkv, wqkvt, 1024, 3072);
  k_tcvt<<<dim3(32, 32), dim3(32, 8), 0, stream>>>(Wproj, wprot, 1024, 1024);
  k_gemm<true><<<dim3(24, 32), 256, 0, stream>>>(xb, wqkvt, qkv, 4096, 3072, 1024);
  k_rope<<<8192, 256, 0, stream>>>(qkv, rsin, rcos, Q, K);
  k_vrep<<<dim3(64, 32), dim3(32, 8), 0, stream>>>(qkv, Vt);
  k_attn<<<512, 256, 0, stream>>>(Q, K, Vt, attn);
  k_gemm64<<<dim3(16, 32), 256, 0, stream>>>(attn, wprot, out, 4096, 1024, 1024);
}

// Round 5
// 194.921 us; speedup vs baseline: 1.0534x; 1.0134x over previous
//
#include <hip/hip_runtime.h>

#define Bb 2
#define Tt 2048
#define Cc_ 1024
#define Hh 16
#define HDd 64

typedef __attribute__((ext_vector_type(8))) short bf16x8;
typedef __attribute__((ext_vector_type(4))) float f32x4;
typedef __attribute__((ext_vector_type(4))) unsigned short u16x4;
typedef __attribute__((ext_vector_type(2))) unsigned int u32x2;

__device__ __forceinline__ unsigned short f2bf(float f) {
  union { float f; unsigned int u; } v; v.f = f;
  unsigned int r = v.u + 0x7FFFu + ((v.u >> 16) & 1u);
  return (unsigned short)(r >> 16);
}
__device__ __forceinline__ float bf2f(unsigned short u) {
  union { unsigned int u; float f; } v; v.u = ((unsigned int)u) << 16;
  return v.f;
}
__device__ __forceinline__ unsigned int cvtpk(float lo, float hi) {
  unsigned int r;
  asm("v_cvt_pk_bf16_f32 %0, %1, %2" : "=v"(r) : "v"(lo), "v"(hi));
  return r;
}
__device__ __forceinline__ f32x4 mfma16(bf16x8 a, bf16x8 b, f32x4 c) {
  return __builtin_amdgcn_mfma_f32_16x16x32_bf16(a, b, c, 0, 0, 0);
}
__device__ __forceinline__ void gl_lds16(const void* g, void* l) {
  auto* gp = reinterpret_cast<const __attribute__((address_space(1))) unsigned int*>(
      reinterpret_cast<unsigned long long>(g));
  auto* lp = reinterpret_cast<__attribute__((address_space(3))) unsigned int*>(
      reinterpret_cast<unsigned long long>(l));
  __builtin_amdgcn_global_load_lds(gp, lp, 16, 0, 0);
}

// ---------------- fp32 -> bf16 elementwise (x) ----------------
__global__ __launch_bounds__(256) void k_cvt(const float* __restrict__ in,
                                             unsigned short* __restrict__ out, int n4) {
  const int i = blockIdx.x * 256 + threadIdx.x;
  if (i >= n4) return;
  f32x4 v = ((const f32x4*)in)[i];
  u16x4 o;
  o[0] = f2bf(v[0]); o[1] = f2bf(v[1]); o[2] = f2bf(v[2]); o[3] = f2bf(v[3]);
  ((u16x4*)out)[i] = o;
}

// ---------------- fp32 [R][Cc] -> bf16 [Cc][R] transpose ----------------
__global__ __launch_bounds__(256) void k_tcvt(const float* __restrict__ in,
                                              unsigned short* __restrict__ out, int R, int Cc) {
  __shared__ float tile[32][33];
  const int c0 = blockIdx.x * 32, r0 = blockIdx.y * 32;
  const int tx = threadIdx.x, ty = threadIdx.y;  // (32,8)
#pragma unroll
  for (int i = 0; i < 4; ++i)
    tile[ty + i * 8][tx] = in[(size_t)(r0 + ty + i * 8) * Cc + c0 + tx];
  __syncthreads();
#pragma unroll
  for (int i = 0; i < 4; ++i)
    out[(size_t)(c0 + ty + i * 8) * R + r0 + tx] = f2bf(tile[tx][ty + i * 8]);
}

// ---------------- bf16 GEMM 128x128: C[M][N] = A[M][K] * Bt[N][K]^T ----------------
template <bool OUT_BF16>
__global__ __launch_bounds__(256) void k_gemm(const unsigned short* __restrict__ A,
                                              const unsigned short* __restrict__ Bt,
                                              void* __restrict__ Cout, int M, int N, int K) {
  __shared__ unsigned short lA[128 * 64];
  __shared__ unsigned short lB[128 * 64];
  const int tid = threadIdx.x;
  const int lane = tid & 63, wid = tid >> 6;
  const int wr = wid >> 1, wc = wid & 1;
  const int bm = blockIdx.y * 128, bn = blockIdx.x * 128;
  const int l15 = lane & 15, l4 = lane >> 4;
  f32x4 acc[4][4];
#pragma unroll
  for (int i = 0; i < 4; ++i)
#pragma unroll
    for (int j = 0; j < 4; ++j) acc[i][j] = f32x4{0.f, 0.f, 0.f, 0.f};
  const int nk = K >> 6;
  for (int t = 0; t < nk; ++t) {
    const int k0 = t << 6;
    __syncthreads();
#pragma unroll
    for (int i = 0; i < 4; ++i) {
      const int slot = i * 256 + tid;
      const int row = slot >> 3, g = slot & 7;
      const int gs = (g ^ (row & 7)) * 8;
      gl_lds16(A + (size_t)(bm + row) * K + k0 + gs, &lA[slot * 8]);
      gl_lds16(Bt + (size_t)(bn + row) * K + k0 + gs, &lB[slot * 8]);
    }
    __syncthreads();
#pragma unroll
    for (int ks = 0; ks < 2; ++ks) {
      bf16x8 af[4], bfr[4];
#pragma unroll
      for (int mf = 0; mf < 4; ++mf) {
        const int row = wr * 64 + mf * 16 + l15;
        const int g = ks * 4 + l4;
        af[mf] = *(const bf16x8*)&lA[row * 64 + ((g ^ (row & 7)) * 8)];
      }
#pragma unroll
      for (int nf = 0; nf < 4; ++nf) {
        const int row = wc * 64 + nf * 16 + l15;
        const int g = ks * 4 + l4;
        bfr[nf] = *(const bf16x8*)&lB[row * 64 + ((g ^ (row & 7)) * 8)];
      }
#pragma unroll
      for (int mf = 0; mf < 4; ++mf)
#pragma unroll
        for (int nf = 0; nf < 4; ++nf)
          acc[mf][nf] = mfma16(af[mf], bfr[nf], acc[mf][nf]);
    }
  }
  const int rb = bm + wr * 64 + l4 * 4;
  const int cb = bn + wc * 64 + l15;
#pragma unroll
  for (int mf = 0; mf < 4; ++mf)
#pragma unroll
    for (int nf = 0; nf < 4; ++nf)
#pragma unroll
      for (int j = 0; j < 4; ++j) {
        const size_t idx = (size_t)(rb + mf * 16 + j) * N + cb + nf * 16;
        if (OUT_BF16)
          ((unsigned short*)Cout)[idx] = f2bf(acc[mf][nf][j]);
        else
          ((float*)Cout)[idx] = acc[mf][nf][j];
      }
}

// ---------------- bf16 GEMM 128x64 tile (for small N): more blocks/CU ----------------
__global__ __launch_bounds__(256) void k_gemm64(const unsigned short* __restrict__ A,
                                                const unsigned short* __restrict__ Bt,
                                                float* __restrict__ Cout, int M, int N, int K) {
  __shared__ unsigned short lA[128 * 64];
  __shared__ unsigned short lB[64 * 64];
  const int tid = threadIdx.x;
  const int lane = tid & 63, w = tid >> 6;  // wave owns rows w*32..w*32+31
  const int bm = blockIdx.y * 128, bn = blockIdx.x * 64;
  const int l15 = lane & 15, l4 = lane >> 4;
  f32x4 acc[2][4];
#pragma unroll
  for (int i = 0; i < 2; ++i)
#pragma unroll
    for (int j = 0; j < 4; ++j) acc[i][j] = f32x4{0.f, 0.f, 0.f, 0.f};
  const int nk = K >> 6;
  for (int t = 0; t < nk; ++t) {
    const int k0 = t << 6;
    __syncthreads();
#pragma unroll
    for (int i = 0; i < 4; ++i) {
      const int slot = i * 256 + tid;
      const int row = slot >> 3, g = slot & 7;
      const int gs = (g ^ (row & 7)) * 8;
      gl_lds16(A + (size_t)(bm + row) * K + k0 + gs, &lA[slot * 8]);
    }
#pragma unroll
    for (int i = 0; i < 2; ++i) {
      const int slot = i * 256 + tid;
      const int row = slot >> 3, g = slot & 7;
      const int gs = (g ^ (row & 7)) * 8;
      gl_lds16(Bt + (size_t)(bn + row) * K + k0 + gs, &lB[slot * 8]);
    }
    __syncthreads();
#pragma unroll
    for (int ks = 0; ks < 2; ++ks) {
      bf16x8 af[2], bfr[4];
#pragma unroll
      for (int mf = 0; mf < 2; ++mf) {
        const int row = w * 32 + mf * 16 + l15;
        const int g = ks * 4 + l4;
        af[mf] = *(const bf16x8*)&lA[row * 64 + ((g ^ (row & 7)) * 8)];
      }
#pragma unroll
      for (int nf = 0; nf < 4; ++nf) {
        const int row = nf * 16 + l15;
        const int g = ks * 4 + l4;
        bfr[nf] = *(const bf16x8*)&lB[row * 64 + ((g ^ (row & 7)) * 8)];
      }
#pragma unroll
      for (int mf = 0; mf < 2; ++mf)
#pragma unroll
        for (int nf = 0; nf < 4; ++nf)
          acc[mf][nf] = mfma16(af[mf], bfr[nf], acc[mf][nf]);
    }
  }
  const int rb = bm + w * 32 + l4 * 4;
  const int cb = bn + l15;
#pragma unroll
  for (int mf = 0; mf < 2; ++mf)
#pragma unroll
    for (int nf = 0; nf < 4; ++nf)
#pragma unroll
      for (int j = 0; j < 4; ++j)
        Cout[(size_t)(rb + mf * 16 + j) * N + cb + nf * 16] = acc[mf][nf][j];
}

// ---------------- RoPE + repack Q,K to [B,H,T,64] bf16 ----------------
// Q pre-scaled by hd^-0.5 * log2(e) so attention works in exp2 domain.
__global__ __launch_bounds__(256) void k_rope(const unsigned short* __restrict__ qkv,
                                              const float* __restrict__ rsin,
                                              const float* __restrict__ rcos,
                                              unsigned short* __restrict__ Q,
                                              unsigned short* __restrict__ K) {
  const int tid = blockIdx.x * 256 + threadIdx.x;  // 2^21 total
  const int d = tid & 31;
  const int t = (tid >> 5) & 2047;
  const int h = (tid >> 16) & 15;
  const int b = tid >> 20;
  const size_t rq = (size_t)(b * Tt + t) * 3072 + h * 192;
  const float q1 = bf2f(qkv[rq + d]), q2 = bf2f(qkv[rq + 32 + d]);
  const float k1 = bf2f(qkv[rq + 64 + d]), k2 = bf2f(qkv[rq + 96 + d]);
  const float s = rsin[t * 32 + d], c = rcos[t * 32 + d];
  const size_t ob = ((size_t)(b * Hh + h) * Tt + t) * 64 + d;
  const float qs = 0.125f * 1.44269504088896f;  // hd^-0.5 * log2(e)
  Q[ob] = f2bf((q1 * c - q2 * s) * qs);
  Q[ob + 32] = f2bf((q1 * s + q2 * c) * qs);
  K[ob] = f2bf(k1 * c - k2 * s);
  K[ob + 32] = f2bf(k1 * s + k2 * c);
}

// ---------------- V repack: qkv v-cols -> Vt [B*H][64][T] bf16 ----------------
__global__ __launch_bounds__(256) void k_vrep(const unsigned short* __restrict__ qkv,
                                              unsigned short* __restrict__ Vt) {
  __shared__ unsigned short tile[32][72];
  const int bh = blockIdx.y;
  const int t0 = blockIdx.x * 32;
  const int tx = threadIdx.x, ty = threadIdx.y;  // (32,8)
  const int b = bh >> 4, h = bh & 15;
#pragma unroll
  for (int i = 0; i < 4; ++i) {
    const int trow = ty + i * 8;
    const size_t r = (size_t)(b * Tt + t0 + trow) * 3072 + h * 192 + 128;
    tile[trow][tx] = qkv[r + tx];
    tile[trow][tx + 32] = qkv[r + 32 + tx];
  }
  __syncthreads();
#pragma unroll
  for (int i = 0; i < 8; ++i) {
    const int d = ty + i * 8;
    Vt[((size_t)bh * 64 + d) * Tt + t0 + tx] = tile[tx][d];
  }
}

// ---------------- causal flash attention ----------------
// 1024 blocks x 256 thr (4 waves), one qtile (QBLK=64) per block, 4 blocks/CU.
// Decode: xcd=bid&7, s=bid>>3, bh=xcd*4+(s>>5), qt from (s&31, s>>5) such that
// each CU's 4 resident blocks sum to exactly 66 tile-steps (static balance) and
// each bh stays on one XCD (L2 locality, proven round 4: FETCH 97->12 MB).
// Per-lane defer-max (no cross-lane ops on common path), per-lane lrun partials,
// cvt_pk bf16 packing, compile-time double-buffer index via 2x unrolled loop.
__global__ __launch_bounds__(256, 4) void k_attn(const unsigned short* __restrict__ Q,
                                                 const unsigned short* __restrict__ Kt,
                                                 const unsigned short* __restrict__ Vt,
                                                 unsigned short* __restrict__ Aout) {
  __shared__ unsigned short lK[2 * 64 * 64];
  __shared__ unsigned short lV[2 * 64 * 64];
  __shared__ unsigned short lP[4 * 16 * 64];
  const int bid = blockIdx.x;
  const int xcd = bid & 7, ss = bid >> 3;
  const int cc = ss & 31, kk = ss >> 5;
  const int bh = xcd * 4 + kk;
  const int c2 = (cc + ((kk & 2) ? 16 : 0)) & 31;
  const int qt = (kk & 1) ? (31 - c2) : c2;
  const int b = bh >> 4, h = bh & 15;
  const int tid = threadIdx.x, lane = tid & 63, w = tid >> 6;
  const int l15 = lane & 15, l4 = lane >> 4;
  const int qb = qt * 64;
  const unsigned short* Kbh = Kt + (size_t)bh * Tt * 64;
  const unsigned short* Vbh = Vt + (size_t)bh * 64 * Tt;

  // ---- precomputed byte offsets (loop-invariant) ----
  // fragment offsets: fo[a][b] = row (a*16+l15), granule (b*4+l4) XOR-swizzled
  int fo[4][2];
#pragma unroll
  for (int a = 0; a < 4; ++a)
#pragma unroll
    for (int bb = 0; bb < 2; ++bb)
      fo[a][bb] = ((a * 16 + l15) * 64 + (((bb * 4 + l4) ^ (l15 & 7)) * 8)) * 2;
  // P-write offsets (row l15, key base nf*16+l4*4)
  int pwo[4];
#pragma unroll
  for (int nf = 0; nf < 4; ++nf)
    pwo[nf] = (l15 * 64 + (((nf * 2 + (l4 >> 1)) ^ (l15 & 7)) * 8) + (l4 & 1) * 4) * 2;
  char* const pB = (char*)lP + w * 2048;
  char* const kB0 = (char*)lK;
  char* const vB0 = (char*)lV;
  // staging offsets: this thread loads rows rA=tid>>3 and rA+32, granule tid&7
  const int rA = tid >> 3;
  const int gsA = ((tid & 7) ^ (rA & 7)) * 8;
  const int kgA = rA * 64 + gsA;              // K tile element offset
  const int vgA = rA * 2048 + gsA;            // V tile element offset (row stride T)
  char* const ldKA = (char*)lK + tid * 16;
  char* const ldVA = (char*)lV + tid * 16;

#define STAGE(BUF, TT)                                                   \
  {                                                                      \
    const int kv_ = (TT) * 64;                                           \
    gl_lds16(Kbh + kv_ * 64 + kgA, ldKA + (BUF) * 8192);                 \
    gl_lds16(Kbh + kv_ * 64 + kgA + 32 * 64, ldKA + (BUF) * 8192 + 4096);\
    gl_lds16(Vbh + kv_ + vgA, ldVA + (BUF) * 8192);                      \
    gl_lds16(Vbh + kv_ + vgA + 32 * 2048, ldVA + (BUF) * 8192 + 4096);   \
  }

  const size_t qoff = ((size_t)bh * Tt + qb + w * 16 + l15) * 64 + l4 * 8;
  const bf16x8 qf0 = *(const bf16x8*)&Q[qoff];
  const bf16x8 qf1 = *(const bf16x8*)&Q[qoff + 32];
  f32x4 o[4];
#pragma unroll
  for (int i = 0; i < 4; ++i) o[i] = f32x4{0.f, 0.f, 0.f, 0.f};
  float mrun = -1e30f, lrun = 0.f;  // stats for q-row (w*16+l15); lrun = per-lane partial
  const int nt = qt + 1;

#define BODY(CUR, T, LASTT)                                                       \
  {                                                                               \
    if ((T) + 1 < nt) STAGE(CUR ^ 1, (T) + 1);                                    \
    f32x4 sv[4];                                                                  \
    _Pragma("unroll") for (int i = 0; i < 4; ++i) sv[i] = f32x4{0.f, 0.f, 0.f, 0.f}; \
    __builtin_amdgcn_s_setprio(1);                                                \
    _Pragma("unroll") for (int ks = 0; ks < 2; ++ks) {                            \
      const bf16x8 qa = ks ? qf1 : qf0;                                           \
      _Pragma("unroll") for (int nf = 0; nf < 4; ++nf) {                          \
        const bf16x8 kf = *(const bf16x8*)(kB0 + (CUR) * 8192 + fo[nf][ks]);      \
        sv[nf] = mfma16(kf, qa, sv[nf]);                                          \
      }                                                                           \
    }                                                                             \
    __builtin_amdgcn_s_setprio(0);                                                \
    if (LASTT) {                                                                  \
      _Pragma("unroll") for (int nf = 0; nf < 4; ++nf)                            \
        _Pragma("unroll") for (int j = 0; j < 4; ++j)                             \
          if (nf * 16 + l4 * 4 + j > w * 16 + l15) sv[nf][j] = -3e38f;            \
    }                                                                             \
    float mx = fmaxf(fmaxf(fmaxf(sv[0][0], sv[0][1]), fmaxf(sv[0][2], sv[0][3])), \
                     fmaxf(fmaxf(sv[1][0], sv[1][1]), fmaxf(sv[1][2], sv[1][3])));\
    mx = fmaxf(mx, fmaxf(fmaxf(fmaxf(sv[2][0], sv[2][1]), fmaxf(sv[2][2], sv[2][3])), \
                         fmaxf(fmaxf(sv[3][0], sv[3][1]), fmaxf(sv[3][2], sv[3][3])))); \
    if (!__all(mx - mrun <= 8.0f)) {                                              \
      mx = fmaxf(mx, __shfl_xor(mx, 16, 64));                                     \
      mx = fmaxf(mx, __shfl_xor(mx, 32, 64));                                     \
      const float mnew = fmaxf(mrun, mx);                                         \
      const float alpha = exp2f(mrun - mnew);                                     \
      lrun *= alpha;                                                              \
      float aj[4];                                                                \
      _Pragma("unroll") for (int j = 0; j < 4; ++j) aj[j] = __shfl(alpha, l4 * 4 + j, 64); \
      _Pragma("unroll") for (int df = 0; df < 4; ++df)                            \
        _Pragma("unroll") for (int j = 0; j < 4; ++j) o[df][j] *= aj[j];          \
      mrun = mnew;                                                                \
    }                                                                             \
    _Pragma("unroll") for (int nf = 0; nf < 4; ++nf) {                            \
      const float p0 = exp2f(sv[nf][0] - mrun), p1 = exp2f(sv[nf][1] - mrun);     \
      const float p2 = exp2f(sv[nf][2] - mrun), p3 = exp2f(sv[nf][3] - mrun);     \
      lrun += (p0 + p1) + (p2 + p3);                                              \
      u32x2 pk; pk[0] = cvtpk(p0, p1); pk[1] = cvtpk(p2, p3);                     \
      *(u32x2*)(pB + pwo[nf]) = pk;                                               \
    }                                                                             \
    __builtin_amdgcn_s_setprio(1);                                                \
    _Pragma("unroll") for (int kb = 0; kb < 2; ++kb) {                            \
      const bf16x8 pa = *(const bf16x8*)(pB + fo[0][kb]);                         \
      _Pragma("unroll") for (int df = 0; df < 4; ++df) {                          \
        const bf16x8 vb = *(const bf16x8*)(vB0 + (CUR) * 8192 + fo[df][kb]);      \
        o[df] = mfma16(pa, vb, o[df]);                                            \
      }                                                                           \
    }                                                                             \
    __builtin_amdgcn_s_setprio(0);                                                \
    if ((T) + 1 < nt) asm volatile("s_waitcnt vmcnt(0)" ::: "memory");            \
    __builtin_amdgcn_s_barrier();                                                 \
  }

  // prologue
  STAGE(0, 0);
  asm volatile("s_waitcnt vmcnt(0)" ::: "memory");
  __builtin_amdgcn_s_barrier();
  int t = 0;
  for (; t + 2 < nt; t += 2) {
    BODY(0, t, false);
    BODY(1, t + 1, false);
  }
  if (nt - t == 2) {
    BODY(0, t, false);
    BODY(1, t + 1, true);
  } else {
    BODY(0, t, true);
  }
#undef BODY
#undef STAGE

  // epilogue: finish per-lane lrun partials -> row totals
  lrun += __shfl_xor(lrun, 16, 64);
  lrun += __shfl_xor(lrun, 32, 64);
  const float rinv = 1.f / lrun;
  float lj[4];
#pragma unroll
  for (int j = 0; j < 4; ++j) lj[j] = __shfl(rinv, l4 * 4 + j, 64);
#pragma unroll
  for (int j = 0; j < 4; ++j) {
    const size_t rr = (size_t)(b * Tt + qb + w * 16 + l4 * 4 + j) * 1024 + h * 64 + l15;
#pragma unroll
    for (int df = 0; df < 4; ++df) Aout[rr + df * 16] = f2bf(o[df][j] * lj[j]);
  }
}

extern "C" void kernel_launch(void* const* d_in, const int* in_sizes, int n_in,
                              void* d_out, int out_size, void* d_ws, size_t ws_size,
                              hipStream_t stream) {
  const float* x = (const float*)d_in[0];
  const float* Wqkv = (const float*)d_in[1];
  const float* Wproj = (const float*)d_in[2];
  const float* rsin = (const float*)d_in[3];
  const float* rcos = (const float*)d_in[4];
  float* out = (float*)d_out;
  char* ws = (char*)d_ws;
  // ws layout (MB): xb 0-8, wqkvt 8-14, wprot 14-16, qkv 16-40, Q 40-48, K 48-56, Vt 56-64, attn 64-72
  unsigned short* xb = (unsigned short*)(ws);
  unsigned short* wqkvt = (unsigned short*)(ws + (size_t)(8 << 20));
  unsigned short* wprot = (unsigned short*)(ws + (size_t)(14 << 20));
  unsigned short* qkv = (unsigned short*)(ws + (size_t)(16 << 20));
  unsigned short* Q = (unsigned short*)(ws + (size_t)(40 << 20));
  unsigned short* K = (unsigned short*)(ws + (size_t)(48 << 20));
  unsigned short* Vt = (unsigned short*)(ws + (size_t)(56 << 20));
  unsigned short* attn = (unsigned short*)(ws + (size_t)(64 << 20));

  k_cvt<<<4096, 256, 0, stream>>>(x, xb, 1048576);
  k_tcvt<<<dim3(96, 32), dim3(32, 8), 0, stream>>>(Wqkv, wqkvt, 1024, 3072);
  k_tcvt<<<dim3(32, 32), dim3(32, 8), 0, stream>>>(Wproj, wprot, 1024, 1024);
  k_gemm<true><<<dim3(24, 32), 256, 0, stream>>>(xb, wqkvt, qkv, 4096, 3072, 1024);
  k_rope<<<8192, 256, 0, stream>>>(qkv, rsin, rcos, Q, K);
  k_vrep<<<dim3(64, 32), dim3(32, 8), 0, stream>>>(qkv, Vt);
  k_attn<<<1024, 256, 0, stream>>>(Q, K, Vt, attn);
  k_gemm64<<<dim3(16, 32), 256, 0, stream>>>(attn, wprot, out, 4096, 1024, 1024);
}

// Round 8
// 186.295 us; speedup vs baseline: 1.1021x; 1.0463x over previous
//
#include <hip/hip_runtime.h>

#define Bb 2
#define Tt 2048
#define Cc_ 1024
#define Hh 16
#define HDd 64

typedef __attribute__((ext_vector_type(8))) short bf16x8;
typedef __attribute__((ext_vector_type(4))) float f32x4;
typedef __attribute__((ext_vector_type(4))) unsigned short u16x4;
typedef __attribute__((ext_vector_type(2))) unsigned int u32x2;

__device__ __forceinline__ unsigned short f2bf(float f) {
  union { float f; unsigned int u; } v; v.f = f;
  unsigned int r = v.u + 0x7FFFu + ((v.u >> 16) & 1u);
  return (unsigned short)(r >> 16);
}
__device__ __forceinline__ float bf2f(unsigned short u) {
  union { unsigned int u; float f; } v; v.u = ((unsigned int)u) << 16;
  return v.f;
}
__device__ __forceinline__ unsigned int cvtpk(float lo, float hi) {
  unsigned int r;
  asm("v_cvt_pk_bf16_f32 %0, %1, %2" : "=v"(r) : "v"(lo), "v"(hi));
  return r;
}
__device__ __forceinline__ f32x4 mfma16(bf16x8 a, bf16x8 b, f32x4 c) {
  return __builtin_amdgcn_mfma_f32_16x16x32_bf16(a, b, c, 0, 0, 0);
}
__device__ __forceinline__ void gl_lds16(const void* g, void* l) {
  auto* gp = reinterpret_cast<const __attribute__((address_space(1))) unsigned int*>(
      reinterpret_cast<unsigned long long>(g));
  auto* lp = reinterpret_cast<__attribute__((address_space(3))) unsigned int*>(
      reinterpret_cast<unsigned long long>(l));
  __builtin_amdgcn_global_load_lds(gp, lp, 16, 0, 0);
}

// ---------------- fused prep: x->bf16 | Wqkv -> permuted-transposed bf16 | Wproj^T ----------------
// Permutation: wqkvt row n (out col of GEMM1): n<1024 -> q head-major (h=n>>6, d=n&63, orig h*192+d)
//              1024..2047 -> k (orig h*192+64+d), 2048.. -> v (orig h*192+128+d).
__global__ __launch_bounds__(256) void k_prep(const float* __restrict__ x,
                                              const float* __restrict__ Wqkv,
                                              const float* __restrict__ Wproj,
                                              unsigned short* __restrict__ xb,
                                              unsigned short* __restrict__ wqkvt,
                                              unsigned short* __restrict__ wprot) {
  const int bid = blockIdx.x;
  const int tid = threadIdx.x;
  if (bid < 4096) {  // x convert: 4M f32 via f32x4
    const int i = bid * 256 + tid;
    f32x4 v = ((const f32x4*)x)[i];
    u16x4 o;
    o[0] = f2bf(v[0]); o[1] = f2bf(v[1]); o[2] = f2bf(v[2]); o[3] = f2bf(v[3]);
    ((u16x4*)xb)[i] = o;
    return;
  }
  __shared__ float tile[32][33];
  const int tx = tid & 31, ty = tid >> 5;  // (32, 8)
  if (bid < 4096 + 3072) {  // Wqkv permuted transpose: out[3072][1024]
    const int tt = bid - 4096;
    const int n0 = (tt % 96) * 32, k0 = (tt / 96) * 32;
    const int region = n0 >> 10, nl = n0 & 1023;
    const int ob = (nl >> 6) * 192 + region * 64 + (nl & 63);  // orig col base (32 consecutive)
#pragma unroll
    for (int i = 0; i < 4; ++i)
      tile[ty + i * 8][tx] = Wqkv[(size_t)(k0 + ty + i * 8) * 3072 + ob + tx];
    __syncthreads();
#pragma unroll
    for (int i = 0; i < 4; ++i)
      wqkvt[(size_t)(n0 + ty + i * 8) * 1024 + k0 + tx] = f2bf(tile[tx][ty + i * 8]);
    return;
  }
  // Wproj transpose: out[1024][1024]
  const int tt = bid - 7168;
  const int c0 = (tt & 31) * 32, r0 = (tt >> 5) * 32;
#pragma unroll
  for (int i = 0; i < 4; ++i)
    tile[ty + i * 8][tx] = Wproj[(size_t)(r0 + ty + i * 8) * 1024 + c0 + tx];
  __syncthreads();
#pragma unroll
  for (int i = 0; i < 4; ++i)
    wprot[(size_t)(c0 + ty + i * 8) * 1024 + r0 + tx] = f2bf(tile[tx][ty + i * 8]);
}

// ---------------- GEMM1 (qkv) with fused RoPE epilogue ----------------
// A = xb [4096][1024], Bt = wqkvt [3072][1024] (permuted). 128x128 tile, grid (24, 32).
// n-tile region: 0-7 q (rope+scale -> Q [bh][T][64]), 8-15 k (rope -> K), 16-23 v (vtmp [4096][1024]).
// Wave quadrant wc = one head; rope pair (d, d+32) = (acc[mf][nf], acc[mf][nf+2]), nf in {0,1}.
__global__ __launch_bounds__(256) void k_gemm_qkv(const unsigned short* __restrict__ A,
                                                  const unsigned short* __restrict__ Bt,
                                                  const float* __restrict__ rsin,
                                                  const float* __restrict__ rcos,
                                                  unsigned short* __restrict__ Qo,
                                                  unsigned short* __restrict__ Ko,
                                                  unsigned short* __restrict__ vtmp) {
  __shared__ unsigned short lA[128 * 64];
  __shared__ unsigned short lB[128 * 64];
  const int K = 1024;
  const int tid = threadIdx.x;
  const int lane = tid & 63, wid = tid >> 6;
  const int wr = wid >> 1, wc = wid & 1;
  const int bm = blockIdx.y * 128, bn = blockIdx.x * 128;
  const int l15 = lane & 15, l4 = lane >> 4;
  f32x4 acc[4][4];
#pragma unroll
  for (int i = 0; i < 4; ++i)
#pragma unroll
    for (int j = 0; j < 4; ++j) acc[i][j] = f32x4{0.f, 0.f, 0.f, 0.f};
  for (int t = 0; t < 16; ++t) {
    const int k0 = t << 6;
    __syncthreads();
#pragma unroll
    for (int i = 0; i < 4; ++i) {
      const int slot = i * 256 + tid;
      const int row = slot >> 3, g = slot & 7;
      const int gs = (g ^ (row & 7)) * 8;
      gl_lds16(A + (size_t)(bm + row) * K + k0 + gs, &lA[slot * 8]);
      gl_lds16(Bt + (size_t)(bn + row) * K + k0 + gs, &lB[slot * 8]);
    }
    __syncthreads();
#pragma unroll
    for (int ks = 0; ks < 2; ++ks) {
      bf16x8 af[4], bfr[4];
#pragma unroll
      for (int mf = 0; mf < 4; ++mf) {
        const int row = wr * 64 + mf * 16 + l15;
        const int g = ks * 4 + l4;
        af[mf] = *(const bf16x8*)&lA[row * 64 + ((g ^ (row & 7)) * 8)];
      }
#pragma unroll
      for (int nf = 0; nf < 4; ++nf) {
        const int row = wc * 64 + nf * 16 + l15;
        const int g = ks * 4 + l4;
        bfr[nf] = *(const bf16x8*)&lB[row * 64 + ((g ^ (row & 7)) * 8)];
      }
#pragma unroll
      for (int mf = 0; mf < 4; ++mf)
#pragma unroll
        for (int nf = 0; nf < 4; ++nf)
          acc[mf][nf] = mfma16(af[mf], bfr[nf], acc[mf][nf]);
    }
  }
  const int rb = bm + wr * 64 + l4 * 4;
  const int region = blockIdx.x >> 3;
  if (region < 2) {  // q or k: rope
    const int h = (blockIdx.x & 7) * 2 + wc;
    unsigned short* dst = (region == 0) ? Qo : Ko;
    const float qs = (region == 0) ? (0.125f * 1.44269504088896f) : 1.0f;
#pragma unroll
    for (int mf = 0; mf < 4; ++mf)
#pragma unroll
      for (int j = 0; j < 4; ++j) {
        const int trow = rb + mf * 16 + j;
        const int bi = trow >> 11, t = trow & 2047;
        const size_t rowb = ((size_t)(bi * Hh + h) * Tt + t) * 64;
#pragma unroll
        for (int nf = 0; nf < 2; ++nf) {
          const int d = nf * 16 + l15;
          const float sn = rsin[t * 32 + d], cs = rcos[t * 32 + d];
          const float a1 = acc[mf][nf][j], a2 = acc[mf][nf + 2][j];
          dst[rowb + d] = f2bf((a1 * cs - a2 * sn) * qs);
          dst[rowb + d + 32] = f2bf((a1 * sn + a2 * cs) * qs);
        }
      }
  } else {  // v: linear [4096][1024], col = h*64 + d
    const int colb = (blockIdx.x & 7) * 128 + wc * 64;
#pragma unroll
    for (int mf = 0; mf < 4; ++mf)
#pragma unroll
      for (int nf = 0; nf < 4; ++nf)
#pragma unroll
        for (int j = 0; j < 4; ++j)
          vtmp[(size_t)(rb + mf * 16 + j) * 1024 + colb + nf * 16 + l15] =
              f2bf(acc[mf][nf][j]);
  }
}

// ---------------- V repack: vtmp [4096][1024] -> Vt [B*H][64][T] bf16 ----------------
__global__ __launch_bounds__(256) void k_vrep(const unsigned short* __restrict__ vtmp,
                                              unsigned short* __restrict__ Vt) {
  __shared__ unsigned short tile[32][72];
  const int bh = blockIdx.y;
  const int t0 = blockIdx.x * 32;
  const int tx = threadIdx.x, ty = threadIdx.y;  // (32,8)
  const int b = bh >> 4, h = bh & 15;
#pragma unroll
  for (int i = 0; i < 4; ++i) {
    const int trow = ty + i * 8;
    const size_t r = (size_t)(b * Tt + t0 + trow) * 1024 + h * 64;
    tile[trow][tx] = vtmp[r + tx];
    tile[trow][tx + 32] = vtmp[r + 32 + tx];
  }
  __syncthreads();
#pragma unroll
  for (int i = 0; i < 8; ++i) {
    const int d = ty + i * 8;
    Vt[((size_t)bh * 64 + d) * Tt + t0 + tx] = tile[tx][d];
  }
}

// ---------------- causal flash attention (unchanged from round 5) ----------------
__global__ __launch_bounds__(256, 4) void k_attn(const unsigned short* __restrict__ Q,
                                                 const unsigned short* __restrict__ Kt,
                                                 const unsigned short* __restrict__ Vt,
                                                 unsigned short* __restrict__ Aout) {
  __shared__ unsigned short lK[2 * 64 * 64];
  __shared__ unsigned short lV[2 * 64 * 64];
  __shared__ unsigned short lP[4 * 16 * 64];
  const int bid = blockIdx.x;
  const int xcd = bid & 7, ss = bid >> 3;
  const int cc = ss & 31, kk = ss >> 5;
  const int bh = xcd * 4 + kk;
  const int c2 = (cc + ((kk & 2) ? 16 : 0)) & 31;
  const int qt = (kk & 1) ? (31 - c2) : c2;
  const int b = bh >> 4, h = bh & 15;
  const int tid = threadIdx.x, lane = tid & 63, w = tid >> 6;
  const int l15 = lane & 15, l4 = lane >> 4;
  const int qb = qt * 64;
  const unsigned short* Kbh = Kt + (size_t)bh * Tt * 64;
  const unsigned short* Vbh = Vt + (size_t)bh * 64 * Tt;

  int fo[4][2];
#pragma unroll
  for (int a = 0; a < 4; ++a)
#pragma unroll
    for (int bb = 0; bb < 2; ++bb)
      fo[a][bb] = ((a * 16 + l15) * 64 + (((bb * 4 + l4) ^ (l15 & 7)) * 8)) * 2;
  int pwo[4];
#pragma unroll
  for (int nf = 0; nf < 4; ++nf)
    pwo[nf] = (l15 * 64 + (((nf * 2 + (l4 >> 1)) ^ (l15 & 7)) * 8) + (l4 & 1) * 4) * 2;
  char* const pB = (char*)lP + w * 2048;
  char* const kB0 = (char*)lK;
  char* const vB0 = (char*)lV;
  const int rA = tid >> 3;
  const int gsA = ((tid & 7) ^ (rA & 7)) * 8;
  const int kgA = rA * 64 + gsA;
  const int vgA = rA * 2048 + gsA;
  char* const ldKA = (char*)lK + tid * 16;
  char* const ldVA = (char*)lV + tid * 16;

#define STAGE(BUF, TT)                                                   \
  {                                                                      \
    const int kv_ = (TT) * 64;                                           \
    gl_lds16(Kbh + kv_ * 64 + kgA, ldKA + (BUF) * 8192);                 \
    gl_lds16(Kbh + kv_ * 64 + kgA + 32 * 64, ldKA + (BUF) * 8192 + 4096);\
    gl_lds16(Vbh + kv_ + vgA, ldVA + (BUF) * 8192);                      \
    gl_lds16(Vbh + kv_ + vgA + 32 * 2048, ldVA + (BUF) * 8192 + 4096);   \
  }

  const size_t qoff = ((size_t)bh * Tt + qb + w * 16 + l15) * 64 + l4 * 8;
  const bf16x8 qf0 = *(const bf16x8*)&Q[qoff];
  const bf16x8 qf1 = *(const bf16x8*)&Q[qoff + 32];
  f32x4 o[4];
#pragma unroll
  for (int i = 0; i < 4; ++i) o[i] = f32x4{0.f, 0.f, 0.f, 0.f};
  float mrun = -1e30f, lrun = 0.f;
  const int nt = qt + 1;

#define BODY(CUR, T, LASTT)                                                       \
  {                                                                               \
    if ((T) + 1 < nt) STAGE(CUR ^ 1, (T) + 1);                                    \
    f32x4 sv[4];                                                                  \
    _Pragma("unroll") for (int i = 0; i < 4; ++i) sv[i] = f32x4{0.f, 0.f, 0.f, 0.f}; \
    __builtin_amdgcn_s_setprio(1);                                                \
    _Pragma("unroll") for (int ks = 0; ks < 2; ++ks) {                            \
      const bf16x8 qa = ks ? qf1 : qf0;                                           \
      _Pragma("unroll") for (int nf = 0; nf < 4; ++nf) {                          \
        const bf16x8 kf = *(const bf16x8*)(kB0 + (CUR) * 8192 + fo[nf][ks]);      \
        sv[nf] = mfma16(kf, qa, sv[nf]);                                          \
      }                                                                           \
    }                                                                             \
    __builtin_amdgcn_s_setprio(0);                                                \
    if (LASTT) {                                                                  \
      _Pragma("unroll") for (int nf = 0; nf < 4; ++nf)                            \
        _Pragma("unroll") for (int j = 0; j < 4; ++j)                             \
          if (nf * 16 + l4 * 4 + j > w * 16 + l15) sv[nf][j] = -3e38f;            \
    }                                                                             \
    float mx = fmaxf(fmaxf(fmaxf(sv[0][0], sv[0][1]), fmaxf(sv[0][2], sv[0][3])), \
                     fmaxf(fmaxf(sv[1][0], sv[1][1]), fmaxf(sv[1][2], sv[1][3])));\
    mx = fmaxf(mx, fmaxf(fmaxf(fmaxf(sv[2][0], sv[2][1]), fmaxf(sv[2][2], sv[2][3])), \
                         fmaxf(fmaxf(sv[3][0], sv[3][1]), fmaxf(sv[3][2], sv[3][3])))); \
    if (!__all(mx - mrun <= 8.0f)) {                                              \
      mx = fmaxf(mx, __shfl_xor(mx, 16, 64));                                     \
      mx = fmaxf(mx, __shfl_xor(mx, 32, 64));                                     \
      const float mnew = fmaxf(mrun, mx);                                         \
      const float alpha = exp2f(mrun - mnew);                                     \
      lrun *= alpha;                                                              \
      float aj[4];                                                                \
      _Pragma("unroll") for (int j = 0; j < 4; ++j) aj[j] = __shfl(alpha, l4 * 4 + j, 64); \
      _Pragma("unroll") for (int df = 0; df < 4; ++df)                            \
        _Pragma("unroll") for (int j = 0; j < 4; ++j) o[df][j] *= aj[j];          \
      mrun = mnew;                                                                \
    }                                                                             \
    _Pragma("unroll") for (int nf = 0; nf < 4; ++nf) {                            \
      const float p0 = exp2f(sv[nf][0] - mrun), p1 = exp2f(sv[nf][1] - mrun);     \
      const float p2 = exp2f(sv[nf][2] - mrun), p3 = exp2f(sv[nf][3] - mrun);     \
      lrun += (p0 + p1) + (p2 + p3);                                              \
      u32x2 pk; pk[0] = cvtpk(p0, p1); pk[1] = cvtpk(p2, p3);                     \
      *(u32x2*)(pB + pwo[nf]) = pk;                                               \
    }                                                                             \
    __builtin_amdgcn_s_setprio(1);                                                \
    _Pragma("unroll") for (int kb = 0; kb < 2; ++kb) {                            \
      const bf16x8 pa = *(const bf16x8*)(pB + fo[0][kb]);                         \
      _Pragma("unroll") for (int df = 0; df < 4; ++df) {                          \
        const bf16x8 vb = *(const bf16x8*)(vB0 + (CUR) * 8192 + fo[df][kb]);      \
        o[df] = mfma16(pa, vb, o[df]);                                            \
      }                                                                           \
    }                                                                             \
    __builtin_amdgcn_s_setprio(0);                                                \
    if ((T) + 1 < nt) asm volatile("s_waitcnt vmcnt(0)" ::: "memory");            \
    __builtin_amdgcn_s_barrier();                                                 \
  }

  STAGE(0, 0);
  asm volatile("s_waitcnt vmcnt(0)" ::: "memory");
  __builtin_amdgcn_s_barrier();
  int t = 0;
  for (; t + 2 < nt; t += 2) {
    BODY(0, t, false);
    BODY(1, t + 1, false);
  }
  if (nt - t == 2) {
    BODY(0, t, false);
    BODY(1, t + 1, true);
  } else {
    BODY(0, t, true);
  }
#undef BODY
#undef STAGE

  lrun += __shfl_xor(lrun, 16, 64);
  lrun += __shfl_xor(lrun, 32, 64);
  const float rinv = 1.f / lrun;
  float lj[4];
#pragma unroll
  for (int j = 0; j < 4; ++j) lj[j] = __shfl(rinv, l4 * 4 + j, 64);
#pragma unroll
  for (int j = 0; j < 4; ++j) {
    const size_t rr = (size_t)(b * Tt + qb + w * 16 + l4 * 4 + j) * 1024 + h * 64 + l15;
#pragma unroll
    for (int df = 0; df < 4; ++df) Aout[rr + df * 16] = f2bf(o[df][j] * lj[j]);
  }
}

// ---------------- GEMM2: attn [4096][1024] x wprot -> out fp32, dbuf prefetch ----------------
// BM=128 BN=64 BK=64, grid (16,32)=512 blocks (2/CU). T3-min: STAGE(next) -> compute -> vmcnt0+barrier.
__global__ __launch_bounds__(256) void k_gemm2(const unsigned short* __restrict__ A,
                                               const unsigned short* __restrict__ Bt,
                                               float* __restrict__ Cout) {
  __shared__ unsigned short lA[2][128 * 64];
  __shared__ unsigned short lB[2][64 * 64];
  const int K = 1024, N = 1024;
  const int tid = threadIdx.x;
  const int lane = tid & 63, w = tid >> 6;
  const int bm = blockIdx.y * 128, bn = blockIdx.x * 64;
  const int l15 = lane & 15, l4 = lane >> 4;
  f32x4 acc[2][4];
#pragma unroll
  for (int i = 0; i < 2; ++i)
#pragma unroll
    for (int j = 0; j < 4; ++j) acc[i][j] = f32x4{0.f, 0.f, 0.f, 0.f};

#define STG(BUF, TT)                                                        \
  {                                                                         \
    const int k0 = (TT) << 6;                                               \
    _Pragma("unroll") for (int i = 0; i < 4; ++i) {                         \
      const int slot = i * 256 + tid;                                       \
      const int row = slot >> 3, g = slot & 7;                              \
      const int gs = (g ^ (row & 7)) * 8;                                   \
      gl_lds16(A + (size_t)(bm + row) * K + k0 + gs, &lA[BUF][slot * 8]);   \
    }                                                                       \
    _Pragma("unroll") for (int i = 0; i < 2; ++i) {                         \
      const int slot = i * 256 + tid;                                       \
      const int row = slot >> 3, g = slot & 7;                              \
      const int gs = (g ^ (row & 7)) * 8;                                   \
      gl_lds16(Bt + (size_t)(bn + row) * K + k0 + gs, &lB[BUF][slot * 8]);  \
    }                                                                       \
  }

  STG(0, 0);
  asm volatile("s_waitcnt vmcnt(0)" ::: "memory");
  __builtin_amdgcn_s_barrier();
  for (int t = 0; t < 16; ++t) {
    const int cur = t & 1;
    if (t + 1 < 16) STG(cur ^ 1, t + 1);
    __builtin_amdgcn_s_setprio(1);
#pragma unroll
    for (int ks = 0; ks < 2; ++ks) {
      bf16x8 af[2], bfr[4];
#pragma unroll
      for (int mf = 0; mf < 2; ++mf) {
        const int row = w * 32 + mf * 16 + l15;
        const int g = ks * 4 + l4;
        af[mf] = *(const bf16x8*)&lA[cur][row * 64 + ((g ^ (row & 7)) * 8)];
      }
#pragma unroll
      for (int nf = 0; nf < 4; ++nf) {
        const int row = nf * 16 + l15;
        const int g = ks * 4 + l4;
        bfr[nf] = *(const bf16x8*)&lB[cur][row * 64 + ((g ^ (row & 7)) * 8)];
      }
#pragma unroll
      for (int mf = 0; mf < 2; ++mf)
#pragma unroll
        for (int nf = 0; nf < 4; ++nf)
          acc[mf][nf] = mfma16(af[mf], bfr[nf], acc[mf][nf]);
    }
    __builtin_amdgcn_s_setprio(0);
    if (t + 1 < 16) asm volatile("s_waitcnt vmcnt(0)" ::: "memory");
    __builtin_amdgcn_s_barrier();
  }
#undef STG
  const int rb = bm + w * 32 + l4 * 4;
  const int cb = bn + l15;
#pragma unroll
  for (int mf = 0; mf < 2; ++mf)
#pragma unroll
    for (int nf = 0; nf < 4; ++nf)
#pragma unroll
      for (int j = 0; j < 4; ++j)
        Cout[(size_t)(rb + mf * 16 + j) * N + cb + nf * 16] = acc[mf][nf][j];
}

extern "C" void kernel_launch(void* const* d_in, const int* in_sizes, int n_in,
                              void* d_out, int out_size, void* d_ws, size_t ws_size,
                              hipStream_t stream) {
  const float* x = (const float*)d_in[0];
  const float* Wqkv = (const float*)d_in[1];
  const float* Wproj = (const float*)d_in[2];
  const float* rsin = (const float*)d_in[3];
  const float* rcos = (const float*)d_in[4];
  float* out = (float*)d_out;
  char* ws = (char*)d_ws;
  // ws (MB): xb 0-8, wqkvt 8-14, wprot 14-16, vtmp 16-24, Q 40-48, K 48-56, Vt 56-64, attn 64-72
  unsigned short* xb = (unsigned short*)(ws);
  unsigned short* wqkvt = (unsigned short*)(ws + (size_t)(8 << 20));
  unsigned short* wprot = (unsigned short*)(ws + (size_t)(14 << 20));
  unsigned short* vtmp = (unsigned short*)(ws + (size_t)(16 << 20));
  unsigned short* Q = (unsigned short*)(ws + (size_t)(40 << 20));
  unsigned short* K = (unsigned short*)(ws + (size_t)(48 << 20));
  unsigned short* Vt = (unsigned short*)(ws + (size_t)(56 << 20));
  unsigned short* attn = (unsigned short*)(ws + (size_t)(64 << 20));

  k_prep<<<8192, 256, 0, stream>>>(x, Wqkv, Wproj, xb, wqkvt, wprot);
  k_gemm_qkv<<<dim3(24, 32), 256, 0, stream>>>(xb, wqkvt, rsin, rcos, Q, K, vtmp);
  k_vrep<<<dim3(64, 32), dim3(32, 8), 0, stream>>>(vtmp, Vt);
  k_attn<<<1024, 256, 0, stream>>>(Q, K, Vt, attn);
  k_gemm2<<<dim3(16, 32), 256, 0, stream>>>(attn, wprot, out);
}

// Round 9
// 176.178 us; speedup vs baseline: 1.1654x; 1.0574x over previous
//
#include <hip/hip_runtime.h>

#define Bb 2
#define Tt 2048
#define Cc_ 1024
#define Hh 16
#define HDd 64

typedef __attribute__((ext_vector_type(8))) short bf16x8;
typedef __attribute__((ext_vector_type(4))) float f32x4;
typedef __attribute__((ext_vector_type(4))) unsigned short u16x4;
typedef __attribute__((ext_vector_type(2))) unsigned int u32x2;

__device__ __forceinline__ unsigned short f2bf(float f) {
  union { float f; unsigned int u; } v; v.f = f;
  unsigned int r = v.u + 0x7FFFu + ((v.u >> 16) & 1u);
  return (unsigned short)(r >> 16);
}
__device__ __forceinline__ float bf2f(unsigned short u) {
  union { unsigned int u; float f; } v; v.u = ((unsigned int)u) << 16;
  return v.f;
}
__device__ __forceinline__ unsigned int cvtpk(float lo, float hi) {
  unsigned int r;
  asm("v_cvt_pk_bf16_f32 %0, %1, %2" : "=v"(r) : "v"(lo), "v"(hi));
  return r;
}
__device__ __forceinline__ f32x4 mfma16(bf16x8 a, bf16x8 b, f32x4 c) {
  return __builtin_amdgcn_mfma_f32_16x16x32_bf16(a, b, c, 0, 0, 0);
}
__device__ __forceinline__ void gl_lds16(const void* g, void* l) {
  auto* gp = reinterpret_cast<const __attribute__((address_space(1))) unsigned int*>(
      reinterpret_cast<unsigned long long>(g));
  auto* lp = reinterpret_cast<__attribute__((address_space(3))) unsigned int*>(
      reinterpret_cast<unsigned long long>(l));
  __builtin_amdgcn_global_load_lds(gp, lp, 16, 0, 0);
}

// ---------------- fused prep: x->bf16 | Wqkv -> permuted-transposed bf16 | Wproj^T ----------------
__global__ __launch_bounds__(256) void k_prep(const float* __restrict__ x,
                                              const float* __restrict__ Wqkv,
                                              const float* __restrict__ Wproj,
                                              unsigned short* __restrict__ xb,
                                              unsigned short* __restrict__ wqkvt,
                                              unsigned short* __restrict__ wprot) {
  const int bid = blockIdx.x;
  const int tid = threadIdx.x;
  if (bid < 4096) {  // x convert
    const int i = bid * 256 + tid;
    f32x4 v = ((const f32x4*)x)[i];
    u16x4 o;
    o[0] = f2bf(v[0]); o[1] = f2bf(v[1]); o[2] = f2bf(v[2]); o[3] = f2bf(v[3]);
    ((u16x4*)xb)[i] = o;
    return;
  }
  __shared__ float tile[32][33];
  const int tx = tid & 31, ty = tid >> 5;  // (32, 8)
  if (bid < 4096 + 3072) {  // Wqkv permuted transpose: out[3072][1024]
    const int tt = bid - 4096;
    const int n0 = (tt % 96) * 32, k0 = (tt / 96) * 32;
    const int region = n0 >> 10, nl = n0 & 1023;
    const int ob = (nl >> 6) * 192 + region * 64 + (nl & 63);
#pragma unroll
    for (int i = 0; i < 4; ++i)
      tile[ty + i * 8][tx] = Wqkv[(size_t)(k0 + ty + i * 8) * 3072 + ob + tx];
    __syncthreads();
#pragma unroll
    for (int i = 0; i < 4; ++i)
      wqkvt[(size_t)(n0 + ty + i * 8) * 1024 + k0 + tx] = f2bf(tile[tx][ty + i * 8]);
    return;
  }
  // Wproj transpose: out[1024][1024]
  const int tt = bid - 7168;
  const int c0 = (tt & 31) * 32, r0 = (tt >> 5) * 32;
#pragma unroll
  for (int i = 0; i < 4; ++i)
    tile[ty + i * 8][tx] = Wproj[(size_t)(r0 + ty + i * 8) * 1024 + c0 + tx];
  __syncthreads();
#pragma unroll
  for (int i = 0; i < 4; ++i)
    wprot[(size_t)(c0 + ty + i * 8) * 1024 + r0 + tx] = f2bf(tile[tx][ty + i * 8]);
}

// ---------------- GEMM1 (qkv): dbuf prefetch main loop, fused RoPE + V-transpose epilogue ------
// A = xb [4096][1024], Bt = wqkvt [3072][1024] (permuted). 128x128 tile, grid (24, 32).
// bn region: 0-7 q (rope+scale -> Q [bh][T][64]), 8-15 k (rope -> K),
//            16-23 v (LDS-transpose -> Vt [bh][64][T] directly; k_vrep eliminated).
__global__ __launch_bounds__(256) void k_gemm_qkv(const unsigned short* __restrict__ A,
                                                  const unsigned short* __restrict__ Bt,
                                                  const float* __restrict__ rsin,
                                                  const float* __restrict__ rcos,
                                                  unsigned short* __restrict__ Qo,
                                                  unsigned short* __restrict__ Ko,
                                                  unsigned short* __restrict__ Vt) {
  __shared__ unsigned short lA[2][128 * 64];
  __shared__ unsigned short lB[2][128 * 64];
  const int K = 1024;
  const int tid = threadIdx.x;
  const int lane = tid & 63, wid = tid >> 6;
  const int wr = wid >> 1, wc = wid & 1;
  const int bm = blockIdx.y * 128, bn = blockIdx.x * 128;
  const int l15 = lane & 15, l4 = lane >> 4;
  f32x4 acc[4][4];
#pragma unroll
  for (int i = 0; i < 4; ++i)
#pragma unroll
    for (int j = 0; j < 4; ++j) acc[i][j] = f32x4{0.f, 0.f, 0.f, 0.f};

#define STG(BUF, TT)                                                        \
  {                                                                         \
    const int k0 = (TT) << 6;                                               \
    _Pragma("unroll") for (int i = 0; i < 4; ++i) {                         \
      const int slot = i * 256 + tid;                                       \
      const int row = slot >> 3, g = slot & 7;                              \
      const int gs = (g ^ (row & 7)) * 8;                                   \
      gl_lds16(A + (size_t)(bm + row) * K + k0 + gs, &lA[BUF][slot * 8]);   \
      gl_lds16(Bt + (size_t)(bn + row) * K + k0 + gs, &lB[BUF][slot * 8]);  \
    }                                                                       \
  }

  STG(0, 0);
  asm volatile("s_waitcnt vmcnt(0)" ::: "memory");
  __builtin_amdgcn_s_barrier();
  for (int t = 0; t < 16; ++t) {
    const int cur = t & 1;
    if (t + 1 < 16) STG(cur ^ 1, t + 1);
    __builtin_amdgcn_s_setprio(1);
#pragma unroll
    for (int ks = 0; ks < 2; ++ks) {
      bf16x8 af[4], bfr[4];
#pragma unroll
      for (int mf = 0; mf < 4; ++mf) {
        const int row = wr * 64 + mf * 16 + l15;
        const int g = ks * 4 + l4;
        af[mf] = *(const bf16x8*)&lA[cur][row * 64 + ((g ^ (row & 7)) * 8)];
      }
#pragma unroll
      for (int nf = 0; nf < 4; ++nf) {
        const int row = wc * 64 + nf * 16 + l15;
        const int g = ks * 4 + l4;
        bfr[nf] = *(const bf16x8*)&lB[cur][row * 64 + ((g ^ (row & 7)) * 8)];
      }
#pragma unroll
      for (int mf = 0; mf < 4; ++mf)
#pragma unroll
        for (int nf = 0; nf < 4; ++nf)
          acc[mf][nf] = mfma16(af[mf], bfr[nf], acc[mf][nf]);
    }
    __builtin_amdgcn_s_setprio(0);
    if (t + 1 < 16) asm volatile("s_waitcnt vmcnt(0)" ::: "memory");
    __builtin_amdgcn_s_barrier();
  }
#undef STG

  const int rb = bm + wr * 64 + l4 * 4;
  const int region = blockIdx.x >> 3;
  if (region < 2) {  // q or k: rope epilogue (fp32, on accumulators)
    const int h = (blockIdx.x & 7) * 2 + wc;
    unsigned short* dst = (region == 0) ? Qo : Ko;
    const float qs = (region == 0) ? (0.125f * 1.44269504088896f) : 1.0f;
#pragma unroll
    for (int mf = 0; mf < 4; ++mf)
#pragma unroll
      for (int j = 0; j < 4; ++j) {
        const int trow = rb + mf * 16 + j;
        const int bi = trow >> 11, t = trow & 2047;
        const size_t rowb = ((size_t)(bi * Hh + h) * Tt + t) * 64;
#pragma unroll
        for (int nf = 0; nf < 2; ++nf) {
          const int d = nf * 16 + l15;
          const float sn = rsin[t * 32 + d], cs = rcos[t * 32 + d];
          const float a1 = acc[mf][nf][j], a2 = acc[mf][nf + 2][j];
          dst[rowb + d] = f2bf((a1 * cs - a2 * sn) * qs);
          dst[rowb + d + 32] = f2bf((a1 * sn + a2 * cs) * qs);
        }
      }
  } else {  // v: LDS transpose -> Vt [bh][64][T] directly
    unsigned short* tp = &lA[0][0];  // reuse staging LDS: [128 t][65 d-pad] bf16 = 16.6 KB
    const int h0 = (blockIdx.x & 7) * 2;
    const int bi = bm >> 11, tbase = bm & 2047;
    const int dd = tid >> 2, t0c = (tid & 3) * 32;
#pragma unroll
    for (int ph = 0; ph < 2; ++ph) {
      if (wc == ph) {
#pragma unroll
        for (int mf = 0; mf < 4; ++mf)
#pragma unroll
          for (int nf = 0; nf < 4; ++nf)
#pragma unroll
            for (int j = 0; j < 4; ++j) {
              const int tl = wr * 64 + mf * 16 + l4 * 4 + j;
              const int dl = nf * 16 + l15;
              tp[tl * 65 + dl] = f2bf(acc[mf][nf][j]);
            }
      }
      __syncthreads();
      const size_t ob = ((size_t)(bi * Hh + h0 + ph) * 64 + dd) * (size_t)Tt + tbase + t0c;
#pragma unroll
      for (int c = 0; c < 8; ++c) {
        u16x4 v4;
#pragma unroll
        for (int e = 0; e < 4; ++e) v4[e] = tp[(t0c + c * 4 + e) * 65 + dd];
        *(u16x4*)&Vt[ob + c * 4] = v4;
      }
      __syncthreads();
    }
  }
}

// ---------------- causal flash attention (unchanged from round 5) ----------------
__global__ __launch_bounds__(256, 4) void k_attn(const unsigned short* __restrict__ Q,
                                                 const unsigned short* __restrict__ Kt,
                                                 const unsigned short* __restrict__ Vt,
                                                 unsigned short* __restrict__ Aout) {
  __shared__ unsigned short lK[2 * 64 * 64];
  __shared__ unsigned short lV[2 * 64 * 64];
  __shared__ unsigned short lP[4 * 16 * 64];
  const int bid = blockIdx.x;
  const int xcd = bid & 7, ss = bid >> 3;
  const int cc = ss & 31, kk = ss >> 5;
  const int bh = xcd * 4 + kk;
  const int c2 = (cc + ((kk & 2) ? 16 : 0)) & 31;
  const int qt = (kk & 1) ? (31 - c2) : c2;
  const int b = bh >> 4, h = bh & 15;
  const int tid = threadIdx.x, lane = tid & 63, w = tid >> 6;
  const int l15 = lane & 15, l4 = lane >> 4;
  const int qb = qt * 64;
  const unsigned short* Kbh = Kt + (size_t)bh * Tt * 64;
  const unsigned short* Vbh = Vt + (size_t)bh * 64 * Tt;

  int fo[4][2];
#pragma unroll
  for (int a = 0; a < 4; ++a)
#pragma unroll
    for (int bb = 0; bb < 2; ++bb)
      fo[a][bb] = ((a * 16 + l15) * 64 + (((bb * 4 + l4) ^ (l15 & 7)) * 8)) * 2;
  int pwo[4];
#pragma unroll
  for (int nf = 0; nf < 4; ++nf)
    pwo[nf] = (l15 * 64 + (((nf * 2 + (l4 >> 1)) ^ (l15 & 7)) * 8) + (l4 & 1) * 4) * 2;
  char* const pB = (char*)lP + w * 2048;
  char* const kB0 = (char*)lK;
  char* const vB0 = (char*)lV;
  const int rA = tid >> 3;
  const int gsA = ((tid & 7) ^ (rA & 7)) * 8;
  const int kgA = rA * 64 + gsA;
  const int vgA = rA * 2048 + gsA;
  char* const ldKA = (char*)lK + tid * 16;
  char* const ldVA = (char*)lV + tid * 16;

#define STAGE(BUF, TT)                                                   \
  {                                                                      \
    const int kv_ = (TT) * 64;                                           \
    gl_lds16(Kbh + kv_ * 64 + kgA, ldKA + (BUF) * 8192);                 \
    gl_lds16(Kbh + kv_ * 64 + kgA + 32 * 64, ldKA + (BUF) * 8192 + 4096);\
    gl_lds16(Vbh + kv_ + vgA, ldVA + (BUF) * 8192);                      \
    gl_lds16(Vbh + kv_ + vgA + 32 * 2048, ldVA + (BUF) * 8192 + 4096);   \
  }

  const size_t qoff = ((size_t)bh * Tt + qb + w * 16 + l15) * 64 + l4 * 8;
  const bf16x8 qf0 = *(const bf16x8*)&Q[qoff];
  const bf16x8 qf1 = *(const bf16x8*)&Q[qoff + 32];
  f32x4 o[4];
#pragma unroll
  for (int i = 0; i < 4; ++i) o[i] = f32x4{0.f, 0.f, 0.f, 0.f};
  float mrun = -1e30f, lrun = 0.f;
  const int nt = qt + 1;

#define BODY(CUR, T, LASTT)                                                       \
  {                                                                               \
    if ((T) + 1 < nt) STAGE(CUR ^ 1, (T) + 1);                                    \
    f32x4 sv[4];                                                                  \
    _Pragma("unroll") for (int i = 0; i < 4; ++i) sv[i] = f32x4{0.f, 0.f, 0.f, 0.f}; \
    __builtin_amdgcn_s_setprio(1);                                                \
    _Pragma("unroll") for (int ks = 0; ks < 2; ++ks) {                            \
      const bf16x8 qa = ks ? qf1 : qf0;                                           \
      _Pragma("unroll") for (int nf = 0; nf < 4; ++nf) {                          \
        const bf16x8 kf = *(const bf16x8*)(kB0 + (CUR) * 8192 + fo[nf][ks]);      \
        sv[nf] = mfma16(kf, qa, sv[nf]);                                          \
      }                                                                           \
    }                                                                             \
    __builtin_amdgcn_s_setprio(0);                                                \
    if (LASTT) {                                                                  \
      _Pragma("unroll") for (int nf = 0; nf < 4; ++nf)                            \
        _Pragma("unroll") for (int j = 0; j < 4; ++j)                             \
          if (nf * 16 + l4 * 4 + j > w * 16 + l15) sv[nf][j] = -3e38f;            \
    }                                                                             \
    float mx = fmaxf(fmaxf(fmaxf(sv[0][0], sv[0][1]), fmaxf(sv[0][2], sv[0][3])), \
                     fmaxf(fmaxf(sv[1][0], sv[1][1]), fmaxf(sv[1][2], sv[1][3])));\
    mx = fmaxf(mx, fmaxf(fmaxf(fmaxf(sv[2][0], sv[2][1]), fmaxf(sv[2][2], sv[2][3])), \
                         fmaxf(fmaxf(sv[3][0], sv[3][1]), fmaxf(sv[3][2], sv[3][3])))); \
    if (!__all(mx - mrun <= 8.0f)) {                                              \
      mx = fmaxf(mx, __shfl_xor(mx, 16, 64));                                     \
      mx = fmaxf(mx, __shfl_xor(mx, 32, 64));                                     \
      const float mnew = fmaxf(mrun, mx);                                         \
      const float alpha = exp2f(mrun - mnew);                                     \
      lrun *= alpha;                                                              \
      float aj[4];                                                                \
      _Pragma("unroll") for (int j = 0; j < 4; ++j) aj[j] = __shfl(alpha, l4 * 4 + j, 64); \
      _Pragma("unroll") for (int df = 0; df < 4; ++df)                            \
        _Pragma("unroll") for (int j = 0; j < 4; ++j) o[df][j] *= aj[j];          \
      mrun = mnew;                                                                \
    }                                                                             \
    _Pragma("unroll") for (int nf = 0; nf < 4; ++nf) {                            \
      const float p0 = exp2f(sv[nf][0] - mrun), p1 = exp2f(sv[nf][1] - mrun);     \
      const float p2 = exp2f(sv[nf][2] - mrun), p3 = exp2f(sv[nf][3] - mrun);     \
      lrun += (p0 + p1) + (p2 + p3);                                              \
      u32x2 pk; pk[0] = cvtpk(p0, p1); pk[1] = cvtpk(p2, p3);                     \
      *(u32x2*)(pB + pwo[nf]) = pk;                                               \
    }                                                                             \
    __builtin_amdgcn_s_setprio(1);                                                \
    _Pragma("unroll") for (int kb = 0; kb < 2; ++kb) {                            \
      const bf16x8 pa = *(const bf16x8*)(pB + fo[0][kb]);                         \
      _Pragma("unroll") for (int df = 0; df < 4; ++df) {                          \
        const bf16x8 vb = *(const bf16x8*)(vB0 + (CUR) * 8192 + fo[df][kb]);      \
        o[df] = mfma16(pa, vb, o[df]);                                            \
      }                                                                           \
    }                                                                             \
    __builtin_amdgcn_s_setprio(0);                                                \
    if ((T) + 1 < nt) asm volatile("s_waitcnt vmcnt(0)" ::: "memory");            \
    __builtin_amdgcn_s_barrier();                                                 \
  }

  STAGE(0, 0);
  asm volatile("s_waitcnt vmcnt(0)" ::: "memory");
  __builtin_amdgcn_s_barrier();
  int t = 0;
  for (; t + 2 < nt; t += 2) {
    BODY(0, t, false);
    BODY(1, t + 1, false);
  }
  if (nt - t == 2) {
    BODY(0, t, false);
    BODY(1, t + 1, true);
  } else {
    BODY(0, t, true);
  }
#undef BODY
#undef STAGE

  lrun += __shfl_xor(lrun, 16, 64);
  lrun += __shfl_xor(lrun, 32, 64);
  const float rinv = 1.f / lrun;
  float lj[4];
#pragma unroll
  for (int j = 0; j < 4; ++j) lj[j] = __shfl(rinv, l4 * 4 + j, 64);
#pragma unroll
  for (int j = 0; j < 4; ++j) {
    const size_t rr = (size_t)(b * Tt + qb + w * 16 + l4 * 4 + j) * 1024 + h * 64 + l15;
#pragma unroll
    for (int df = 0; df < 4; ++df) Aout[rr + df * 16] = f2bf(o[df][j] * lj[j]);
  }
}

// ---------------- GEMM2: attn [4096][1024] x wprot -> out fp32, dbuf prefetch ----------------
__global__ __launch_bounds__(256) void k_gemm2(const unsigned short* __restrict__ A,
                                               const unsigned short* __restrict__ Bt,
                                               float* __restrict__ Cout) {
  __shared__ unsigned short lA[2][128 * 64];
  __shared__ unsigned short lB[2][64 * 64];
  const int K = 1024, N = 1024;
  const int tid = threadIdx.x;
  const int lane = tid & 63, w = tid >> 6;
  const int bm = blockIdx.y * 128, bn = blockIdx.x * 64;
  const int l15 = lane & 15, l4 = lane >> 4;
  f32x4 acc[2][4];
#pragma unroll
  for (int i = 0; i < 2; ++i)
#pragma unroll
    for (int j = 0; j < 4; ++j) acc[i][j] = f32x4{0.f, 0.f, 0.f, 0.f};

#define STG(BUF, TT)                                                        \
  {                                                                         \
    const int k0 = (TT) << 6;                                               \
    _Pragma("unroll") for (int i = 0; i < 4; ++i) {                         \
      const int slot = i * 256 + tid;                                       \
      const int row = slot >> 3, g = slot & 7;                              \
      const int gs = (g ^ (row & 7)) * 8;                                   \
      gl_lds16(A + (size_t)(bm + row) * K + k0 + gs, &lA[BUF][slot * 8]);   \
    }                                                                       \
    _Pragma("unroll") for (int i = 0; i < 2; ++i) {                         \
      const int slot = i * 256 + tid;                                       \
      const int row = slot >> 3, g = slot & 7;                              \
      const int gs = (g ^ (row & 7)) * 8;                                   \
      gl_lds16(Bt + (size_t)(bn + row) * K + k0 + gs, &lB[BUF][slot * 8]);  \
    }                                                                       \
  }

  STG(0, 0);
  asm volatile("s_waitcnt vmcnt(0)" ::: "memory");
  __builtin_amdgcn_s_barrier();
  for (int t = 0; t < 16; ++t) {
    const int cur = t & 1;
    if (t + 1 < 16) STG(cur ^ 1, t + 1);
    __builtin_amdgcn_s_setprio(1);
#pragma unroll
    for (int ks = 0; ks < 2; ++ks) {
      bf16x8 af[2], bfr[4];
#pragma unroll
      for (int mf = 0; mf < 2; ++mf) {
        const int row = w * 32 + mf * 16 + l15;
        const int g = ks * 4 + l4;
        af[mf] = *(const bf16x8*)&lA[cur][row * 64 + ((g ^ (row & 7)) * 8)];
      }
#pragma unroll
      for (int nf = 0; nf < 4; ++nf) {
        const int row = nf * 16 + l15;
        const int g = ks * 4 + l4;
        bfr[nf] = *(const bf16x8*)&lB[cur][row * 64 + ((g ^ (row & 7)) * 8)];
      }
#pragma unroll
      for (int mf = 0; mf < 2; ++mf)
#pragma unroll
        for (int nf = 0; nf < 4; ++nf)
          acc[mf][nf] = mfma16(af[mf], bfr[nf], acc[mf][nf]);
    }
    __builtin_amdgcn_s_setprio(0);
    if (t + 1 < 16) asm volatile("s_waitcnt vmcnt(0)" ::: "memory");
    __builtin_amdgcn_s_barrier();
  }
#undef STG
  const int rb = bm + w * 32 + l4 * 4;
  const int cb = bn + l15;
#pragma unroll
  for (int mf = 0; mf < 2; ++mf)
#pragma unroll
    for (int nf = 0; nf < 4; ++nf)
#pragma unroll
      for (int j = 0; j < 4; ++j)
        Cout[(size_t)(rb + mf * 16 + j) * N + cb + nf * 16] = acc[mf][nf][j];
}

extern "C" void kernel_launch(void* const* d_in, const int* in_sizes, int n_in,
                              void* d_out, int out_size, void* d_ws, size_t ws_size,
                              hipStream_t stream) {
  const float* x = (const float*)d_in[0];
  const float* Wqkv = (const float*)d_in[1];
  const float* Wproj = (const float*)d_in[2];
  const float* rsin = (const float*)d_in[3];
  const float* rcos = (const float*)d_in[4];
  float* out = (float*)d_out;
  char* ws = (char*)d_ws;
  // ws (MB): xb 0-8, wqkvt 8-14, wprot 14-16, Q 40-48, K 48-56, Vt 56-64, attn 64-72
  unsigned short* xb = (unsigned short*)(ws);
  unsigned short* wqkvt = (unsigned short*)(ws + (size_t)(8 << 20));
  unsigned short* wprot = (unsigned short*)(ws + (size_t)(14 << 20));
  unsigned short* Q = (unsigned short*)(ws + (size_t)(40 << 20));
  unsigned short* K = (unsigned short*)(ws + (size_t)(48 << 20));
  unsigned short* Vt = (unsigned short*)(ws + (size_t)(56 << 20));
  unsigned short* attn = (unsigned short*)(ws + (size_t)(64 << 20));

  k_prep<<<8192, 256, 0, stream>>>(x, Wqkv, Wproj, xb, wqkvt, wprot);
  k_gemm_qkv<<<dim3(24, 32), 256, 0, stream>>>(xb, wqkvt, rsin, rcos, Q, K, Vt);
  k_attn<<<1024, 256, 0, stream>>>(Q, K, Vt, attn);
  k_gemm2<<<dim3(16, 32), 256, 0, stream>>>(attn, wprot, out);
}